// Round 8
// baseline (674.190 us; speedup 1.0000x reference)
//
#include <hip/hip_runtime.h>
#include <stdint.h>

#define B_ROWS 131072
#define SCALE 0.0625f
#define LN_EPS 1e-5f
#define ATTN_EPS 1e-8f

#define BIG_BLOCKS 512
#define BIG_THREADS 512
#define ROWS_PER_BLOCK (B_ROWS / BIG_BLOCKS)   // 256
#define ROWS_PER_WAVE  (ROWS_PER_BLOCK / 8)    // 32 (8 waves/block)
#define NSLICE 64                              // 64 atomic accumulation slices

// ---- workspace layout (float offsets) ----
#define WS_PARTU 0
#define WS_PARTS (WS_PARTU + 512*4096)           // 2097152 (only 64*4096 used)
#define WS_U     (WS_PARTS + 512*16)             // 2105344
#define WS_S     (WS_U + 4096)                   // 2109440
#define WS_SLOTS (WS_S + 64)                     // 2109504
#define WS_MID   (WS_SLOTS + 4096)               // 2113600
#define WS_GX    (WS_MID + 4096)                 // 2117696
#define WS_GH    (WS_GX + 12288)                 // 2129984
#define WS_H1    (WS_GH + 12288)                 // 2142272
#define WS_QKG   (WS_H1 + 4096)                  // 2146368
#define WS_QB    (WS_QKG + 4096)                 // 2150464
#define WS_WIHV  (WS_QB + 64)                    // 2150528
#define WS_BGX   (WS_WIHV + 196608)              // 2347136
#define WS_WQKG  (WS_BGX + 768)                  // 2347904
#define WS_U2G   (WS_WQKG + 65536)               // 2413440
#define WS_U1    (WS_U2G + 256)                  // 2413696
#define WS_C1    (WS_U1 + 256)                   // 2413952

// =====================================================================
// K_pre1: weight compositions, 257 blocks (R3 restructure, ~10us)
// + zero the 64-slice PARTU/PARTS accumulators (re-zeroed every replay).
// =====================================================================
__global__ __launch_bounds__(256) void k_pre1(
    const float* __restrict__ Wq, const float* __restrict__ bq,
    const float* __restrict__ Wk, const float* __restrict__ bk,
    const float* __restrict__ Wv, const float* __restrict__ bv,
    const float* __restrict__ W_ih, const float* __restrict__ b_ih,
    const float* __restrict__ g_in, const float* __restrict__ be_in,
    float* __restrict__ ws)
{
  int bid = blockIdx.x, t = threadIdx.x;
  int wave = t >> 6, lane = t & 63;
  // zero atomic accumulators: blocks 0..255 cover 64*4096; block 256 PARTS
  if (bid < 256) {
#pragma unroll
    for (int q = 0; q < 4; q++)
      ws[WS_PARTU + bid * 1024 + q * 256 + t] = 0.f;
  } else {
#pragma unroll
    for (int q = 0; q < 4; q++)
      ws[WS_PARTS + q * 256 + t] = 0.f;
  }
  if (bid < 192) {
    __shared__ __align__(16) float sW[4 * 256];
    __shared__ __align__(16) float sBv[256];
    int j0 = bid * 4;
#pragma unroll
    for (int r = 0; r < 4; r++) sW[r * 256 + t] = W_ih[(j0 + r) * 256 + t];
    sBv[t] = bv[t];
    __syncthreads();
    int d = t;
    float a0 = 0.f, a1 = 0.f, a2 = 0.f, a3 = 0.f;
#pragma unroll 8
    for (int dd = 0; dd < 256; dd++) {
      float v = Wv[dd * 256 + d];
      a0 = fmaf(sW[0 * 256 + dd], v, a0);
      a1 = fmaf(sW[1 * 256 + dd], v, a1);
      a2 = fmaf(sW[2 * 256 + dd], v, a2);
      a3 = fmaf(sW[3 * 256 + dd], v, a3);
    }
    ws[WS_WIHV + (j0 + 0) * 256 + d] = a0;
    ws[WS_WIHV + (j0 + 1) * 256 + d] = a1;
    ws[WS_WIHV + (j0 + 2) * 256 + d] = a2;
    ws[WS_WIHV + (j0 + 3) * 256 + d] = a3;
    float s = 0.f;
#pragma unroll
    for (int q = 0; q < 4; q++) {
      int idx = lane * 4 + q;
      s = fmaf(sW[wave * 256 + idx], sBv[idx], s);
    }
#pragma unroll
    for (int m = 1; m <= 32; m <<= 1) s += __shfl_xor(s, m);
    if (lane == 0) ws[WS_BGX + j0 + wave] = b_ih[j0 + wave] + s;
  } else if (bid < 256) {
    __shared__ __align__(16) float sKc[4 * 256];
    __shared__ __align__(16) float sBq[256];
    int c0 = (bid - 192) * 4;
#pragma unroll
    for (int r = 0; r < 4; r++) sKc[r * 256 + t] = Wk[t * 256 + c0 + r];
    sBq[t] = bq[t];
    __syncthreads();
    int d = t;
    float a0 = 0.f, a1 = 0.f, a2 = 0.f, a3 = 0.f;
#pragma unroll 8
    for (int i = 0; i < 256; i++) {
      float wq = Wq[i * 256 + d];
      a0 = fmaf(wq, sKc[0 * 256 + i], a0);
      a1 = fmaf(wq, sKc[1 * 256 + i], a1);
      a2 = fmaf(wq, sKc[2 * 256 + i], a2);
      a3 = fmaf(wq, sKc[3 * 256 + i], a3);
    }
    ws[WS_WQKG + (c0 + 0) * 256 + d] = SCALE * g_in[c0 + 0] * a0;
    ws[WS_WQKG + (c0 + 1) * 256 + d] = SCALE * g_in[c0 + 1] * a1;
    ws[WS_WQKG + (c0 + 2) * 256 + d] = SCALE * g_in[c0 + 2] * a2;
    ws[WS_WQKG + (c0 + 3) * 256 + d] = SCALE * g_in[c0 + 3] * a3;
    float s = 0.f;
#pragma unroll
    for (int q = 0; q < 4; q++) {
      int idx = lane * 4 + q;
      s = fmaf(sBq[idx], sKc[wave * 256 + idx], s);
    }
#pragma unroll
    for (int m = 1; m <= 32; m <<= 1) s += __shfl_xor(s, m);
    if (lane == 0) ws[WS_U2G + c0 + wave] = SCALE * g_in[c0 + wave] * s;
  } else {
    __shared__ __align__(16) float sBe[256];
    __shared__ __align__(16) float sT2[256];
    sBe[t] = be_in[t];
    __syncthreads();
    float a = 0.f;
#pragma unroll 8
    for (int dp = 0; dp < 256; dp += 4) {
      float4 w = *(const float4*)(Wk + t * 256 + dp);
      a = fmaf(w.x, sBe[dp], fmaf(w.y, sBe[dp + 1],
          fmaf(w.z, sBe[dp + 2], fmaf(w.w, sBe[dp + 3], a))));
    }
    sT2[t] = a + bk[t];
    __syncthreads();
    float u = 0.f;
#pragma unroll 8
    for (int i = 0; i < 256; i++)
      u = fmaf(Wq[i * 256 + t], sT2[i], u);
    ws[WS_U1 + t] = u;
    if (wave == 0) {
      float s = 0.f;
#pragma unroll
      for (int q = 0; q < 4; q++) {
        int idx = lane * 4 + q;
        s = fmaf(bq[idx], sT2[idx], s);
      }
#pragma unroll
      for (int m = 1; m <= 32; m <<= 1) s += __shfl_xor(s, m);
      if (lane == 0) ws[WS_C1] = s;
    }
  }
}

// =====================================================================
// K_qkg: s = LN(slots); qkg/qb. init: slots = mu + sigma*noise.
// =====================================================================
__global__ __launch_bounds__(256) void k_qkg(
    const float* __restrict__ noise, const float* __restrict__ mu,
    const float* __restrict__ sigma, const float* __restrict__ g_s,
    const float* __restrict__ be_s, float* __restrict__ ws, int init)
{
  __shared__ __align__(16) float sS[16 * 260];
  __shared__ __align__(16) float sAux[512];
  __shared__ __align__(16) float sStat[32];
  int bid = blockIdx.x, t = threadIdx.x;
  for (int n = 0; n < 16; n++) {
    float v;
    if (init) v = fmaf(sigma[t], noise[n * 256 + t], mu[t]);
    else      v = ws[WS_SLOTS + n * 256 + t];
    sS[n * 260 + t] = v;
    if (init && bid == 0) ws[WS_SLOTS + n * 256 + t] = v;
  }
  __syncthreads();
  { int n = t >> 4, c = t & 15;
    float s1 = 0.f, s2 = 0.f;
    for (int k = 0; k < 16; k++) {
      float x = sS[n * 260 + c * 16 + k];
      s1 += x; s2 = fmaf(x, x, s2);
    }
    sAux[n * 16 + c] = s1; sAux[256 + n * 16 + c] = s2; }
  __syncthreads();
  if (t < 16) {
    float s1 = 0.f, s2 = 0.f;
    for (int c = 0; c < 16; c++) { s1 += sAux[t * 16 + c]; s2 += sAux[256 + t * 16 + c]; }
    float m = s1 * (1.f / 256.f);
    float v = fmaxf(fmaf(-m, m, s2 * (1.f / 256.f)), 0.f);
    sStat[t] = m; sStat[16 + t] = rsqrtf(v + LN_EPS);
  }
  __syncthreads();
  { float gs = g_s[t], bs = be_s[t];
    for (int n = 0; n < 16; n++) {
      float m = sStat[n], rs = sStat[16 + n];
      sS[n * 260 + t] = fmaf((sS[n * 260 + t] - m) * rs, gs, bs);
    } }
  __syncthreads();
  if (bid < 64) {
    int cr = t >> 6, n = (t >> 2) & 15, ks = t & 3;
    int c = bid * 4 + cr;
    const float* wrow = ws + WS_WQKG + c * 256 + ks * 64;
    const float* srow = &sS[n * 260 + ks * 64];
    float acc = 0.f;
#pragma unroll
    for (int i = 0; i < 16; i++) {
      float4 w = *(const float4*)(wrow + i * 4);
      float4 s4 = *(const float4*)(srow + i * 4);
      acc = fmaf(w.x, s4.x, fmaf(w.y, s4.y, fmaf(w.z, s4.z, fmaf(w.w, s4.w, acc))));
    }
    sAux[t] = acc;
    __syncthreads();
    if (t < 64) {
      int cr2 = t >> 4, n2 = t & 15;
      int c2 = bid * 4 + cr2;
      int b = cr2 * 64 + n2 * 4;
      float s = sAux[b] + sAux[b + 1] + sAux[b + 2] + sAux[b + 3];
      ws[WS_QKG + n2 * 256 + c2] = s + ws[WS_U2G + c2];
    }
  } else {
    int n = t >> 4, ks = t & 15;
    float acc = 0.f;
    for (int k = 0; k < 16; k++)
      acc = fmaf(sS[n * 260 + ks * 16 + k], ws[WS_U1 + ks * 16 + k], acc);
    sAux[t] = acc;
    __syncthreads();
    if (t < 16) {
      float s = 0.f;
      for (int k = 0; k < 16; k++) s += sAux[t * 16 + k];
      ws[WS_QB + t] = SCALE * (s + ws[WS_C1]);
    }
  }
}

// =====================================================================
// K_big: 512 threads, 8 waves, 32 rows/wave, 4-ROW ILP (8 chains/SIMD).
// Loads issued at loop top (no prefetch regs — stall amortizes over 4
// rows, covered by co-resident waves); frees regs for the 4th chain.
// Peak regs ~ x(64)+qw(64)+P(64)+temps ~ 240, inside (512,2)'s 256.
// Epilogue: atomicAdd into 64 shared slices (validated R7, +1.7us).
// =====================================================================
__global__ __launch_bounds__(512, 2) void k_big(
    const float* __restrict__ X, float* __restrict__ ws)
{
  __shared__ __align__(16) float red[4 * 4096];   // 64 KB
  __shared__ __align__(16) float redS[128];       // 8 waves x 16
  int t = threadIdx.x;
  int wave = t >> 6, lane = t & 63;
  int p = lane >> 4, g = lane & 15;

  const float* qkg = ws + WS_QKG;
  float qw[4][16];
  float qs[4];
#pragma unroll
  for (int i = 0; i < 4; i++) {
    const float* rp = qkg + (4 * p + i) * 256 + g * 16;
#pragma unroll
    for (int jq = 0; jq < 4; jq++) {
      float4 v4 = *(const float4*)(rp + 4 * jq);
      qw[i][4 * jq + 0] = v4.x; qw[i][4 * jq + 1] = v4.y;
      qw[i][4 * jq + 2] = v4.z; qw[i][4 * jq + 3] = v4.w;
    }
    float s = 0.f;
#pragma unroll
    for (int j = 0; j < 16; j++) s += qw[i][j];
    qs[i] = s;
  }
#pragma unroll
  for (int m = 1; m <= 8; m <<= 1) {
#pragma unroll
    for (int i = 0; i < 4; i++) qs[i] += __shfl_xor(qs[i], m);
  }
  float qb0[4];
  {
    float4 q4 = *(const float4*)(ws + WS_QB + 4 * p);
    qb0[0] = q4.x; qb0[1] = q4.y; qb0[2] = q4.z; qb0[3] = q4.w;
  }

  float P[4][16];
#pragma unroll
  for (int i = 0; i < 4; i++)
#pragma unroll
    for (int j = 0; j < 16; j++) P[i][j] = 0.f;
  float Q[4] = {0.f, 0.f, 0.f, 0.f};
  float Sa[4] = {0.f, 0.f, 0.f, 0.f};

  size_t rowbase = (size_t)blockIdx.x * ROWS_PER_BLOCK + (size_t)wave * ROWS_PER_WAVE;
  const float* base = X + rowbase * 256 + g * 16;

#pragma unroll 1
  for (int r = 0; r < ROWS_PER_WAVE; r += 4) {
    const float* rp = base + (size_t)r * 256;
    float x[4][16];
#pragma unroll
    for (int i = 0; i < 4; i++) {
      float4 a = *(const float4*)(rp + i * 256 + 0);
      float4 b = *(const float4*)(rp + i * 256 + 4);
      float4 c = *(const float4*)(rp + i * 256 + 8);
      float4 d = *(const float4*)(rp + i * 256 + 12);
      x[i][0] = a.x; x[i][1] = a.y; x[i][2] = a.z; x[i][3] = a.w;
      x[i][4] = b.x; x[i][5] = b.y; x[i][6] = b.z; x[i][7] = b.w;
      x[i][8] = c.x; x[i][9] = c.y; x[i][10] = c.z; x[i][11] = c.w;
      x[i][12] = d.x; x[i][13] = d.y; x[i][14] = d.z; x[i][15] = d.w;
    }

    // ---- stats, 4 rows interleaved ----
    float s1[4] = {0.f, 0.f, 0.f, 0.f};
    float s2[4] = {0.f, 0.f, 0.f, 0.f};
#pragma unroll
    for (int j = 0; j < 16; j++) {
#pragma unroll
      for (int i = 0; i < 4; i++) {
        s1[i] += x[i][j];
        s2[i] = fmaf(x[i][j], x[i][j], s2[i]);
      }
    }
#pragma unroll
    for (int m = 1; m <= 8; m <<= 1) {
#pragma unroll
      for (int i = 0; i < 4; i++) {
        s1[i] += __shfl_xor(s1[i], m);
        s2[i] += __shfl_xor(s2[i], m);
      }
    }
    float rs[4], mrs[4];
#pragma unroll
    for (int i = 0; i < 4; i++) {
      float mean = s1[i] * (1.f / 256.f);
      float var = fmaxf(fmaf(-mean, mean, s2[i] * (1.f / 256.f)), 0.f);
      rs[i] = rsqrtf(var + LN_EPS);
      mrs[i] = mean * rs[i];
    }

    // ---- dots, 4 rows x 4 slots interleaved ----
    float dd[4][4];
#pragma unroll
    for (int i = 0; i < 4; i++)
#pragma unroll
      for (int sl = 0; sl < 4; sl++) dd[i][sl] = 0.f;
#pragma unroll
    for (int j = 0; j < 16; j++) {
#pragma unroll
      for (int i = 0; i < 4; i++) {
#pragma unroll
        for (int sl = 0; sl < 4; sl++)
          dd[i][sl] = fmaf(qw[sl][j], x[i][j], dd[i][sl]);
      }
    }
#pragma unroll
    for (int m = 1; m <= 8; m <<= 1) {
#pragma unroll
      for (int i = 0; i < 4; i++) {
#pragma unroll
        for (int sl = 0; sl < 4; sl++)
          dd[i][sl] += __shfl_xor(dd[i][sl], m);
      }
    }

    // ---- softmax, 4 rows interleaved ----
    float ar[4][4], av[4][4];
#pragma unroll
    for (int i = 0; i < 4; i++) {
      float dsc[4];
#pragma unroll
      for (int sl = 0; sl < 4; sl++)
        dsc[sl] = fmaf(rs[i], dd[i][sl], fmaf(-mrs[i], qs[sl], qb0[sl]));
      float mx = fmaxf(fmaxf(dsc[0], dsc[1]), fmaxf(dsc[2], dsc[3]));
      mx = fmaxf(mx, __shfl_xor(mx, 16));
      mx = fmaxf(mx, __shfl_xor(mx, 32));
      float e[4];
#pragma unroll
      for (int sl = 0; sl < 4; sl++) e[sl] = __expf(dsc[sl] - mx);
      float se = e[0] + e[1] + e[2] + e[3];
      se += __shfl_xor(se, 16);
      se += __shfl_xor(se, 32);
      float inv = 1.0f / se;
#pragma unroll
      for (int sl = 0; sl < 4; sl++) {
        av[i][sl] = fmaf(e[sl], inv, ATTN_EPS);
        ar[i][sl] = av[i][sl] * rs[i];
      }
    }

    // ---- P accumulation ----
#pragma unroll
    for (int j = 0; j < 16; j++) {
#pragma unroll
      for (int i = 0; i < 4; i++) {
#pragma unroll
        for (int sl = 0; sl < 4; sl++)
          P[sl][j] = fmaf(ar[i][sl], x[i][j], P[sl][j]);
      }
    }
#pragma unroll
    for (int i = 0; i < 4; i++) {
#pragma unroll
      for (int sl = 0; sl < 4; sl++) {
        Q[sl] = fmaf(av[i][sl], mrs[i], Q[sl]);
        Sa[sl] += av[i][sl];
      }
    }
  }

  // Two-stage cross-wave reduce in 64KB LDS (Uy = P - Q per slot/elem).
  int slot = wave & 3;
  if (wave < 4) {
#pragma unroll
    for (int i = 0; i < 4; i++) {
#pragma unroll
      for (int jq = 0; jq < 4; jq++) {
        float4 v4;
        v4.x = P[i][4 * jq + 0] - Q[i]; v4.y = P[i][4 * jq + 1] - Q[i];
        v4.z = P[i][4 * jq + 2] - Q[i]; v4.w = P[i][4 * jq + 3] - Q[i];
        *(float4*)&red[slot * 4096 + (4 * p + i) * 256 + g * 16 + jq * 4] = v4;
      }
    }
  }
  if (g == 0) {
#pragma unroll
    for (int i = 0; i < 4; i++) redS[wave * 16 + 4 * p + i] = Sa[i];
  }
  __syncthreads();
  if (wave >= 4) {
#pragma unroll
    for (int i = 0; i < 4; i++) {
#pragma unroll
      for (int jq = 0; jq < 4; jq++) {
        float4* dst = (float4*)&red[slot * 4096 + (4 * p + i) * 256 + g * 16 + jq * 4];
        float4 c = *dst;
        c.x += P[i][4 * jq + 0] - Q[i]; c.y += P[i][4 * jq + 1] - Q[i];
        c.z += P[i][4 * jq + 2] - Q[i]; c.w += P[i][4 * jq + 3] - Q[i];
        *dst = c;
      }
    }
  }
  __syncthreads();
  int slice = blockIdx.x & 63;
#pragma unroll
  for (int k = 0; k < 8; k++) {
    int idx = k * 512 + t;
    float v = red[idx] + red[4096 + idx] + red[8192 + idx] + red[12288 + idx];
    atomicAdd(&ws[WS_PARTU + (size_t)slice * 4096 + idx], v);
  }
  if (t < 16) {
    float sv = 0.f;
#pragma unroll
    for (int w = 0; w < 8; w++) sv += redS[w * 16 + t];
    atomicAdd(&ws[WS_PARTS + slice * 16 + t], sv);
  }
}

// =====================================================================
// K_red: reduce 64 atomic slices -> U[16][256], S[16]; self-zeros the
// slices for the next iteration (1MB input vs old 8MB: ~4us vs ~15).
// =====================================================================
__global__ __launch_bounds__(256) void k_red(float* __restrict__ ws)
{
  __shared__ __align__(16) float sAux[256];
  int bid = blockIdx.x, t = threadIdx.x;
  if (bid < 256) {
    int el = t & 15, wg = t >> 4;
    int e = bid * 16 + el;
    float acc = 0.f;
#pragma unroll
    for (int k = 0; k < 4; k++) {
      size_t idx = WS_PARTU + (size_t)(wg + k * 16) * 4096 + e;
      acc += ws[idx];
      ws[idx] = 0.f;
    }
    sAux[t] = acc;
    __syncthreads();
    if (t < 16) {
      float s = 0.f;
      for (int w = 0; w < 16; w++) s += sAux[w * 16 + t];
      ws[WS_U + bid * 16 + t] = s;
    }
  } else {
    int n = t & 15, wg = t >> 4;
    float acc = 0.f;
#pragma unroll
    for (int k = 0; k < 4; k++) {
      int idx = WS_PARTS + (wg + k * 16) * 16 + n;
      acc += ws[idx];
      ws[idx] = 0.f;
    }
    sAux[t] = acc;
    __syncthreads();
    if (t < 16) {
      float s = 0.f;
      for (int w = 0; w < 16; w++) s += sAux[w * 16 + t];
      ws[WS_S + t] = s;
    }
  }
}

// =====================================================================
// K_gxgh: bid<64:  gx[n][j] = W_ihv[j]·(g_in*(U[n]/S[n]) + be_in) + bgx[j]
//         bid>=64: gh[n][j] = W_hh[j]·slots_prev[n] + b_hh[j]
// =====================================================================
__global__ __launch_bounds__(256) void k_gxgh(
    const float* __restrict__ W_hh, const float* __restrict__ b_hh,
    const float* __restrict__ g_in, const float* __restrict__ be_in,
    float* __restrict__ ws)
{
  __shared__ __align__(16) float sU[16 * 260];
  __shared__ __align__(16) float sInv[16];
  int bid = blockIdx.x, t = threadIdx.x;
  bool isgx = bid < 64;
  if (isgx && t < 16) sInv[t] = 1.0f / ws[WS_S + t];
  __syncthreads();
  if (isgx) {
    float gi = g_in[t], bi = be_in[t];
    for (int n = 0; n < 16; n++)
      sU[n * 260 + t] = fmaf(gi * ws[WS_U + n * 256 + t], sInv[n], bi);
  } else {
    for (int n = 0; n < 16; n++)
      sU[n * 260 + t] = ws[WS_SLOTS + n * 256 + t];
  }
  __syncthreads();
  int jr = t >> 4, n = t & 15;
  if (jr < 12) {
    int j = (isgx ? bid : bid - 64) * 12 + jr;
    const float* srow = &sU[n * 260];
    const float* wrow = isgx ? (ws + WS_WIHV + j * 256) : (W_hh + j * 256);
    float acc = isgx ? ws[WS_BGX + j] : b_hh[j];
#pragma unroll 8
    for (int k = 0; k < 64; k++) {
      float4 w = *(const float4*)(wrow + k * 4);
      float4 s4 = *(const float4*)(srow + k * 4);
      acc = fmaf(w.x, s4.x, fmaf(w.y, s4.y, fmaf(w.z, s4.z, fmaf(w.w, s4.w, acc))));
    }
    if (isgx) ws[WS_GX + n * 768 + j] = acc;
    else      ws[WS_GH + n * 768 + j] = acc;
  }
}

// =====================================================================
// K_midh1: GRU gates -> slots_mid; LN(g_f,be_f); h1 = relu(lnf@W1.T + b1)
// =====================================================================
__global__ __launch_bounds__(256) void k_midh1(
    const float* __restrict__ W1, const float* __restrict__ b1,
    const float* __restrict__ g_f, const float* __restrict__ be_f,
    float* __restrict__ ws)
{
  __shared__ __align__(16) float sM[16 * 260];
  __shared__ __align__(16) float sAux[512];
  __shared__ __align__(16) float sStat[32];
  int bid = blockIdx.x, t = threadIdx.x;
  for (int n = 0; n < 16; n++) {
    float xr = ws[WS_GX + n * 768 + t],       hr = ws[WS_GH + n * 768 + t];
    float xz = ws[WS_GX + n * 768 + 256 + t], hz = ws[WS_GH + n * 768 + 256 + t];
    float xn = ws[WS_GX + n * 768 + 512 + t], hn = ws[WS_GH + n * 768 + 512 + t];
    float sp = ws[WS_SLOTS + n * 256 + t];
    float r = 1.f / (1.f + __expf(-(xr + hr)));
    float z = 1.f / (1.f + __expf(-(xz + hz)));
    float nn = tanhf(fmaf(r, hn, xn));
    float mid = fmaf(z, sp - nn, nn);
    sM[n * 260 + t] = mid;
    if (bid == 0) ws[WS_MID + n * 256 + t] = mid;
  }
  __syncthreads();
  { int n = t >> 4, c = t & 15;
    float s1 = 0.f, s2 = 0.f;
    for (int k = 0; k < 16; k++) {
      float x = sM[n * 260 + c * 16 + k];
      s1 += x; s2 = fmaf(x, x, s2);
    }
    sAux[n * 16 + c] = s1; sAux[256 + n * 16 + c] = s2; }
  __syncthreads();
  if (t < 16) {
    float s1 = 0.f, s2 = 0.f;
    for (int c = 0; c < 16; c++) { s1 += sAux[t * 16 + c]; s2 += sAux[256 + t * 16 + c]; }
    float m = s1 * (1.f / 256.f);
    float v = fmaxf(fmaf(-m, m, s2 * (1.f / 256.f)), 0.f);
    sStat[t] = m; sStat[16 + t] = rsqrtf(v + LN_EPS);
  }
  __syncthreads();
  { float gf = g_f[t], bf = be_f[t];
    for (int n = 0; n < 16; n++) {
      float m = sStat[n], rs = sStat[16 + n];
      sM[n * 260 + t] = fmaf((sM[n * 260 + t] - m) * rs, gf, bf);
    } }
  __syncthreads();
  int jr = t >> 6, n = (t >> 2) & 15, ks = t & 3;
  int j = bid * 4 + jr;
  const float* wrow = W1 + j * 256 + ks * 64;
  const float* srow = &sM[n * 260 + ks * 64];
  float acc = 0.f;
#pragma unroll
  for (int k = 0; k < 16; k++) {
    float4 w = *(const float4*)(wrow + k * 4);
    float4 s4 = *(const float4*)(srow + k * 4);
    acc = fmaf(w.x, s4.x, fmaf(w.y, s4.y, fmaf(w.z, s4.z, fmaf(w.w, s4.w, acc))));
  }
  sAux[t] = acc;
  __syncthreads();
  if (t < 64) {
    int jr2 = t >> 4, n2 = t & 15;
    int j2 = bid * 4 + jr2;
    int b = jr2 * 64 + n2 * 4;
    float s = sAux[b] + sAux[b + 1] + sAux[b + 2] + sAux[b + 3] + b1[j2];
    ws[WS_H1 + n2 * 256 + j2] = fmaxf(s, 0.f);
  }
}

// =====================================================================
// K_ffnew: ff = h1@W2.T + b2;  slots_new = slots_mid + ff -> ws.slots, d_out
// =====================================================================
__global__ __launch_bounds__(256) void k_ffnew(
    const float* __restrict__ W2, const float* __restrict__ b2v,
    float* __restrict__ out, float* __restrict__ ws)
{
  __shared__ __align__(16) float sH[16 * 260];
  __shared__ __align__(16) float sAux[256];
  int bid = blockIdx.x, t = threadIdx.x;
  for (int n = 0; n < 16; n++)
    sH[n * 260 + t] = ws[WS_H1 + n * 256 + t];
  __syncthreads();
  int dr = t >> 6, n = (t >> 2) & 15, ks = t & 3;
  int d = bid * 4 + dr;
  const float* wrow = W2 + d * 256 + ks * 64;
  const float* srow = &sH[n * 260 + ks * 64];
  float acc = 0.f;
#pragma unroll
  for (int k = 0; k < 16; k++) {
    float4 w = *(const float4*)(wrow + k * 4);
    float4 s4 = *(const float4*)(srow + k * 4);
    acc = fmaf(w.x, s4.x, fmaf(w.y, s4.y, fmaf(w.z, s4.z, fmaf(w.w, s4.w, acc))));
  }
  sAux[t] = acc;
  __syncthreads();
  if (t < 64) {
    int dr2 = t >> 4, n2 = t & 15;
    int d2 = bid * 4 + dr2;
    int b = dr2 * 64 + n2 * 4;
    float s = sAux[b] + sAux[b + 1] + sAux[b + 2] + sAux[b + 3]
            + b2v[d2] + ws[WS_MID + n2 * 256 + d2];
    ws[WS_SLOTS + n2 * 256 + d2] = s;
    out[n2 * 256 + d2] = s;
  }
}

// =====================================================================
extern "C" void kernel_launch(void* const* d_in, const int* in_sizes, int n_in,
                              void* d_out, int out_size, void* d_ws, size_t ws_size,
                              hipStream_t stream)
{
  (void)in_sizes; (void)n_in; (void)out_size; (void)ws_size;
  const float* inputs = (const float*)d_in[0];
  const float* noise  = (const float*)d_in[1];
  const float* mu     = (const float*)d_in[2];
  const float* sigma  = (const float*)d_in[3];
  const float* Wq     = (const float*)d_in[4];
  const float* bq     = (const float*)d_in[5];
  const float* Wk     = (const float*)d_in[6];
  const float* bk     = (const float*)d_in[7];
  const float* Wv     = (const float*)d_in[8];
  const float* bv     = (const float*)d_in[9];
  const float* W_ih   = (const float*)d_in[10];
  const float* W_hh   = (const float*)d_in[11];
  const float* b_ih   = (const float*)d_in[12];
  const float* b_hh   = (const float*)d_in[13];
  const float* W1     = (const float*)d_in[14];
  const float* b1     = (const float*)d_in[15];
  const float* W2     = (const float*)d_in[16];
  const float* b2     = (const float*)d_in[17];
  const float* g_in   = (const float*)d_in[18];
  const float* be_in  = (const float*)d_in[19];
  const float* g_s    = (const float*)d_in[20];
  const float* be_s   = (const float*)d_in[21];
  const float* g_f    = (const float*)d_in[22];
  const float* be_f   = (const float*)d_in[23];
  float* ws = (float*)d_ws;
  float* out = (float*)d_out;

  hipLaunchKernelGGL(k_pre1, dim3(257), dim3(256), 0, stream,
                     Wq, bq, Wk, bk, Wv, bv, W_ih, b_ih, g_in, be_in, ws);
  hipLaunchKernelGGL(k_qkg, dim3(65), dim3(256), 0, stream,
                     noise, mu, sigma, g_s, be_s, ws, 1);
  for (int it = 0; it < 3; it++) {
    hipLaunchKernelGGL(k_big, dim3(BIG_BLOCKS), dim3(BIG_THREADS), 0, stream, inputs, ws);
    hipLaunchKernelGGL(k_red, dim3(257), dim3(256), 0, stream, ws);
    hipLaunchKernelGGL(k_gxgh, dim3(128), dim3(256), 0, stream,
                       W_hh, b_hh, g_in, be_in, ws);
    hipLaunchKernelGGL(k_midh1, dim3(64), dim3(256), 0, stream,
                       W1, b1, g_f, be_f, ws);
    hipLaunchKernelGGL(k_ffnew, dim3(64), dim3(256), 0, stream,
                       W2, b2, out, ws);
    if (it < 2)
      hipLaunchKernelGGL(k_qkg, dim3(65), dim3(256), 0, stream,
                         noise, mu, sigma, g_s, be_s, ws, 0);
  }
}

// Round 9
// 557.474 us; speedup vs baseline: 1.2094x; 1.2094x over previous
//
#include <hip/hip_runtime.h>
#include <stdint.h>

#define B_ROWS 131072
#define SCALE 0.0625f
#define LN_EPS 1e-5f
#define ATTN_EPS 1e-8f

#define BIG_BLOCKS 512
#define BIG_THREADS 512
#define ROWS_PER_BLOCK (B_ROWS / BIG_BLOCKS)   // 256
#define ROWS_PER_WAVE  (ROWS_PER_BLOCK / 8)    // 32 (8 waves/block)
#define NSLICE 64                              // 64 atomic accumulation slices

// ---- workspace layout (float offsets) ----
#define WS_PARTU 0
#define WS_PARTS (WS_PARTU + 512*4096)           // 2097152 (only 64*4096 used)
#define WS_U     (WS_PARTS + 512*16)             // 2105344
#define WS_S     (WS_U + 4096)                   // 2109440
#define WS_SLOTS (WS_S + 64)                     // 2109504
#define WS_MID   (WS_SLOTS + 4096)               // 2113600
#define WS_GX    (WS_MID + 4096)                 // 2117696
#define WS_GH    (WS_GX + 12288)                 // 2129984
#define WS_H1    (WS_GH + 12288)                 // 2142272
#define WS_QKG   (WS_H1 + 4096)                  // 2146368
#define WS_QB    (WS_QKG + 4096)                 // 2150464
#define WS_WIHV  (WS_QB + 64)                    // 2150528
#define WS_BGX   (WS_WIHV + 196608)              // 2347136
#define WS_WQKG  (WS_BGX + 768)                  // 2347904
#define WS_U2G   (WS_WQKG + 65536)               // 2413440
#define WS_U1    (WS_U2G + 256)                  // 2413696
#define WS_C1    (WS_U1 + 256)                   // 2413952

// =====================================================================
// K_pre1: weight compositions, 257 blocks (R3 restructure, ~10us)
// + zero the 64-slice PARTU/PARTS accumulators (re-zeroed every replay).
// =====================================================================
__global__ __launch_bounds__(256) void k_pre1(
    const float* __restrict__ Wq, const float* __restrict__ bq,
    const float* __restrict__ Wk, const float* __restrict__ bk,
    const float* __restrict__ Wv, const float* __restrict__ bv,
    const float* __restrict__ W_ih, const float* __restrict__ b_ih,
    const float* __restrict__ g_in, const float* __restrict__ be_in,
    float* __restrict__ ws)
{
  int bid = blockIdx.x, t = threadIdx.x;
  int wave = t >> 6, lane = t & 63;
  // zero atomic accumulators: blocks 0..255 cover 64*4096; block 256 PARTS
  if (bid < 256) {
#pragma unroll
    for (int q = 0; q < 4; q++)
      ws[WS_PARTU + bid * 1024 + q * 256 + t] = 0.f;
  } else {
#pragma unroll
    for (int q = 0; q < 4; q++)
      ws[WS_PARTS + q * 256 + t] = 0.f;
  }
  if (bid < 192) {
    __shared__ __align__(16) float sW[4 * 256];
    __shared__ __align__(16) float sBv[256];
    int j0 = bid * 4;
#pragma unroll
    for (int r = 0; r < 4; r++) sW[r * 256 + t] = W_ih[(j0 + r) * 256 + t];
    sBv[t] = bv[t];
    __syncthreads();
    int d = t;
    float a0 = 0.f, a1 = 0.f, a2 = 0.f, a3 = 0.f;
#pragma unroll 8
    for (int dd = 0; dd < 256; dd++) {
      float v = Wv[dd * 256 + d];
      a0 = fmaf(sW[0 * 256 + dd], v, a0);
      a1 = fmaf(sW[1 * 256 + dd], v, a1);
      a2 = fmaf(sW[2 * 256 + dd], v, a2);
      a3 = fmaf(sW[3 * 256 + dd], v, a3);
    }
    ws[WS_WIHV + (j0 + 0) * 256 + d] = a0;
    ws[WS_WIHV + (j0 + 1) * 256 + d] = a1;
    ws[WS_WIHV + (j0 + 2) * 256 + d] = a2;
    ws[WS_WIHV + (j0 + 3) * 256 + d] = a3;
    float s = 0.f;
#pragma unroll
    for (int q = 0; q < 4; q++) {
      int idx = lane * 4 + q;
      s = fmaf(sW[wave * 256 + idx], sBv[idx], s);
    }
#pragma unroll
    for (int m = 1; m <= 32; m <<= 1) s += __shfl_xor(s, m);
    if (lane == 0) ws[WS_BGX + j0 + wave] = b_ih[j0 + wave] + s;
  } else if (bid < 256) {
    __shared__ __align__(16) float sKc[4 * 256];
    __shared__ __align__(16) float sBq[256];
    int c0 = (bid - 192) * 4;
#pragma unroll
    for (int r = 0; r < 4; r++) sKc[r * 256 + t] = Wk[t * 256 + c0 + r];
    sBq[t] = bq[t];
    __syncthreads();
    int d = t;
    float a0 = 0.f, a1 = 0.f, a2 = 0.f, a3 = 0.f;
#pragma unroll 8
    for (int i = 0; i < 256; i++) {
      float wq = Wq[i * 256 + d];
      a0 = fmaf(wq, sKc[0 * 256 + i], a0);
      a1 = fmaf(wq, sKc[1 * 256 + i], a1);
      a2 = fmaf(wq, sKc[2 * 256 + i], a2);
      a3 = fmaf(wq, sKc[3 * 256 + i], a3);
    }
    ws[WS_WQKG + (c0 + 0) * 256 + d] = SCALE * g_in[c0 + 0] * a0;
    ws[WS_WQKG + (c0 + 1) * 256 + d] = SCALE * g_in[c0 + 1] * a1;
    ws[WS_WQKG + (c0 + 2) * 256 + d] = SCALE * g_in[c0 + 2] * a2;
    ws[WS_WQKG + (c0 + 3) * 256 + d] = SCALE * g_in[c0 + 3] * a3;
    float s = 0.f;
#pragma unroll
    for (int q = 0; q < 4; q++) {
      int idx = lane * 4 + q;
      s = fmaf(sBq[idx], sKc[wave * 256 + idx], s);
    }
#pragma unroll
    for (int m = 1; m <= 32; m <<= 1) s += __shfl_xor(s, m);
    if (lane == 0) ws[WS_U2G + c0 + wave] = SCALE * g_in[c0 + wave] * s;
  } else {
    __shared__ __align__(16) float sBe[256];
    __shared__ __align__(16) float sT2[256];
    sBe[t] = be_in[t];
    __syncthreads();
    float a = 0.f;
#pragma unroll 8
    for (int dp = 0; dp < 256; dp += 4) {
      float4 w = *(const float4*)(Wk + t * 256 + dp);
      a = fmaf(w.x, sBe[dp], fmaf(w.y, sBe[dp + 1],
          fmaf(w.z, sBe[dp + 2], fmaf(w.w, sBe[dp + 3], a))));
    }
    sT2[t] = a + bk[t];
    __syncthreads();
    float u = 0.f;
#pragma unroll 8
    for (int i = 0; i < 256; i++)
      u = fmaf(Wq[i * 256 + t], sT2[i], u);
    ws[WS_U1 + t] = u;
    if (wave == 0) {
      float s = 0.f;
#pragma unroll
      for (int q = 0; q < 4; q++) {
        int idx = lane * 4 + q;
        s = fmaf(bq[idx], sT2[idx], s);
      }
#pragma unroll
      for (int m = 1; m <= 32; m <<= 1) s += __shfl_xor(s, m);
      if (lane == 0) ws[WS_C1] = s;
    }
  }
}

// =====================================================================
// K_qkg: s = LN(slots); qkg/qb. init: slots = mu + sigma*noise.
// =====================================================================
__global__ __launch_bounds__(256) void k_qkg(
    const float* __restrict__ noise, const float* __restrict__ mu,
    const float* __restrict__ sigma, const float* __restrict__ g_s,
    const float* __restrict__ be_s, float* __restrict__ ws, int init)
{
  __shared__ __align__(16) float sS[16 * 260];
  __shared__ __align__(16) float sAux[512];
  __shared__ __align__(16) float sStat[32];
  int bid = blockIdx.x, t = threadIdx.x;
  for (int n = 0; n < 16; n++) {
    float v;
    if (init) v = fmaf(sigma[t], noise[n * 256 + t], mu[t]);
    else      v = ws[WS_SLOTS + n * 256 + t];
    sS[n * 260 + t] = v;
    if (init && bid == 0) ws[WS_SLOTS + n * 256 + t] = v;
  }
  __syncthreads();
  { int n = t >> 4, c = t & 15;
    float s1 = 0.f, s2 = 0.f;
    for (int k = 0; k < 16; k++) {
      float x = sS[n * 260 + c * 16 + k];
      s1 += x; s2 = fmaf(x, x, s2);
    }
    sAux[n * 16 + c] = s1; sAux[256 + n * 16 + c] = s2; }
  __syncthreads();
  if (t < 16) {
    float s1 = 0.f, s2 = 0.f;
    for (int c = 0; c < 16; c++) { s1 += sAux[t * 16 + c]; s2 += sAux[256 + t * 16 + c]; }
    float m = s1 * (1.f / 256.f);
    float v = fmaxf(fmaf(-m, m, s2 * (1.f / 256.f)), 0.f);
    sStat[t] = m; sStat[16 + t] = rsqrtf(v + LN_EPS);
  }
  __syncthreads();
  { float gs = g_s[t], bs = be_s[t];
    for (int n = 0; n < 16; n++) {
      float m = sStat[n], rs = sStat[16 + n];
      sS[n * 260 + t] = fmaf((sS[n * 260 + t] - m) * rs, gs, bs);
    } }
  __syncthreads();
  if (bid < 64) {
    int cr = t >> 6, n = (t >> 2) & 15, ks = t & 3;
    int c = bid * 4 + cr;
    const float* wrow = ws + WS_WQKG + c * 256 + ks * 64;
    const float* srow = &sS[n * 260 + ks * 64];
    float acc = 0.f;
#pragma unroll
    for (int i = 0; i < 16; i++) {
      float4 w = *(const float4*)(wrow + i * 4);
      float4 s4 = *(const float4*)(srow + i * 4);
      acc = fmaf(w.x, s4.x, fmaf(w.y, s4.y, fmaf(w.z, s4.z, fmaf(w.w, s4.w, acc))));
    }
    sAux[t] = acc;
    __syncthreads();
    if (t < 64) {
      int cr2 = t >> 4, n2 = t & 15;
      int c2 = bid * 4 + cr2;
      int b = cr2 * 64 + n2 * 4;
      float s = sAux[b] + sAux[b + 1] + sAux[b + 2] + sAux[b + 3];
      ws[WS_QKG + n2 * 256 + c2] = s + ws[WS_U2G + c2];
    }
  } else {
    int n = t >> 4, ks = t & 15;
    float acc = 0.f;
    for (int k = 0; k < 16; k++)
      acc = fmaf(sS[n * 260 + ks * 16 + k], ws[WS_U1 + ks * 16 + k], acc);
    sAux[t] = acc;
    __syncthreads();
    if (t < 16) {
      float s = 0.f;
      for (int k = 0; k < 16; k++) s += sAux[t * 16 + k];
      ws[WS_QB + t] = SCALE * (s + ws[WS_C1]);
    }
  }
}

// =====================================================================
// K_big: pair-ILP + distance-1 prefetch (R5/R7 structure — 98us known
// good; R8 proved dropping prefetch costs +50us). ONE change vs R7:
// the stats butterfly (4 vars) and dots butterfly (8 vars) are MERGED
// into a single 12-var 4-level butterfly — halves the dependent shuffle
// depth per row-pair; per-variable add order unchanged (same numerics).
// Epilogue: atomicAdd into 64 shared slices (validated R7, +1.7us).
// =====================================================================
__global__ __launch_bounds__(512, 2) void k_big(
    const float* __restrict__ X, float* __restrict__ ws)
{
  __shared__ __align__(16) float red[4 * 4096];   // 64 KB
  __shared__ __align__(16) float redS[128];       // 8 waves x 16
  int t = threadIdx.x;
  int wave = t >> 6, lane = t & 63;
  int p = lane >> 4, g = lane & 15;

  const float* qkg = ws + WS_QKG;
  float qw[4][16];
  float qs[4];
#pragma unroll
  for (int i = 0; i < 4; i++) {
    const float* rp = qkg + (4 * p + i) * 256 + g * 16;
#pragma unroll
    for (int jq = 0; jq < 4; jq++) {
      float4 v4 = *(const float4*)(rp + 4 * jq);
      qw[i][4 * jq + 0] = v4.x; qw[i][4 * jq + 1] = v4.y;
      qw[i][4 * jq + 2] = v4.z; qw[i][4 * jq + 3] = v4.w;
    }
    float s = 0.f;
#pragma unroll
    for (int j = 0; j < 16; j++) s += qw[i][j];
    qs[i] = s;
  }
#pragma unroll
  for (int m = 1; m <= 8; m <<= 1) {
#pragma unroll
    for (int i = 0; i < 4; i++) qs[i] += __shfl_xor(qs[i], m);
  }
  float qb0[4];
  {
    float4 q4 = *(const float4*)(ws + WS_QB + 4 * p);
    qb0[0] = q4.x; qb0[1] = q4.y; qb0[2] = q4.z; qb0[3] = q4.w;
  }

  float P[4][16];
#pragma unroll
  for (int i = 0; i < 4; i++)
#pragma unroll
    for (int j = 0; j < 16; j++) P[i][j] = 0.f;
  float Q[4] = {0.f, 0.f, 0.f, 0.f};
  float Sa[4] = {0.f, 0.f, 0.f, 0.f};

  size_t rowbase = (size_t)blockIdx.x * ROWS_PER_BLOCK + (size_t)wave * ROWS_PER_WAVE;
  const float* base = X + rowbase * 256 + g * 16;

  float4 cA0 = *(const float4*)(base + 0);
  float4 cB0 = *(const float4*)(base + 4);
  float4 cC0 = *(const float4*)(base + 8);
  float4 cD0 = *(const float4*)(base + 12);
  float4 cA1 = *(const float4*)(base + 256);
  float4 cB1 = *(const float4*)(base + 260);
  float4 cC1 = *(const float4*)(base + 264);
  float4 cD1 = *(const float4*)(base + 268);

#pragma unroll 1
  for (int r = 0; r < ROWS_PER_WAVE; r += 2) {
    const float* nx = base + (size_t)((r + 2 < ROWS_PER_WAVE) ? (r + 2) : 0) * 256;
    float4 pA0 = *(const float4*)(nx + 0);
    float4 pB0 = *(const float4*)(nx + 4);
    float4 pC0 = *(const float4*)(nx + 8);
    float4 pD0 = *(const float4*)(nx + 12);
    float4 pA1 = *(const float4*)(nx + 256);
    float4 pB1 = *(const float4*)(nx + 260);
    float4 pC1 = *(const float4*)(nx + 264);
    float4 pD1 = *(const float4*)(nx + 268);

    float x0[16], x1[16];
    x0[0] = cA0.x; x0[1] = cA0.y; x0[2] = cA0.z; x0[3] = cA0.w;
    x0[4] = cB0.x; x0[5] = cB0.y; x0[6] = cB0.z; x0[7] = cB0.w;
    x0[8] = cC0.x; x0[9] = cC0.y; x0[10] = cC0.z; x0[11] = cC0.w;
    x0[12] = cD0.x; x0[13] = cD0.y; x0[14] = cD0.z; x0[15] = cD0.w;
    x1[0] = cA1.x; x1[1] = cA1.y; x1[2] = cA1.z; x1[3] = cA1.w;
    x1[4] = cB1.x; x1[5] = cB1.y; x1[6] = cB1.z; x1[7] = cB1.w;
    x1[8] = cC1.x; x1[9] = cC1.y; x1[10] = cC1.z; x1[11] = cC1.w;
    x1[12] = cD1.x; x1[13] = cD1.y; x1[14] = cD1.z; x1[15] = cD1.w;

    // ---- partial sums: stats AND dots together (12 parallel chains) ----
    float s10 = 0.f, s20 = 0.f, s11 = 0.f, s21 = 0.f;
    float d0[4] = {0.f, 0.f, 0.f, 0.f};
    float d1[4] = {0.f, 0.f, 0.f, 0.f};
#pragma unroll
    for (int j = 0; j < 16; j++) {
      s10 += x0[j]; s20 = fmaf(x0[j], x0[j], s20);
      s11 += x1[j]; s21 = fmaf(x1[j], x1[j], s21);
#pragma unroll
      for (int i = 0; i < 4; i++) {
        d0[i] = fmaf(qw[i][j], x0[j], d0[i]);
        d1[i] = fmaf(qw[i][j], x1[j], d1[i]);
      }
    }
    // ---- ONE merged 12-var butterfly (4 levels over 16 lanes) ----
#pragma unroll
    for (int m = 1; m <= 8; m <<= 1) {
      s10 += __shfl_xor(s10, m); s11 += __shfl_xor(s11, m);
      s20 += __shfl_xor(s20, m); s21 += __shfl_xor(s21, m);
#pragma unroll
      for (int i = 0; i < 4; i++) {
        d0[i] += __shfl_xor(d0[i], m);
        d1[i] += __shfl_xor(d1[i], m);
      }
    }
    float mean0 = s10 * (1.f / 256.f), mean1 = s11 * (1.f / 256.f);
    float var0 = fmaxf(fmaf(-mean0, mean0, s20 * (1.f / 256.f)), 0.f);
    float var1 = fmaxf(fmaf(-mean1, mean1, s21 * (1.f / 256.f)), 0.f);
    float rs0 = rsqrtf(var0 + LN_EPS), rs1 = rsqrtf(var1 + LN_EPS);
    float mrs0 = mean0 * rs0, mrs1 = mean1 * rs1;

    float dsc0[4], dsc1[4];
#pragma unroll
    for (int i = 0; i < 4; i++) {
      dsc0[i] = fmaf(rs0, d0[i], fmaf(-mrs0, qs[i], qb0[i]));
      dsc1[i] = fmaf(rs1, d1[i], fmaf(-mrs1, qs[i], qb0[i]));
    }

    // ---- softmax, both rows interleaved ----
    float mx0 = fmaxf(fmaxf(dsc0[0], dsc0[1]), fmaxf(dsc0[2], dsc0[3]));
    float mx1 = fmaxf(fmaxf(dsc1[0], dsc1[1]), fmaxf(dsc1[2], dsc1[3]));
    mx0 = fmaxf(mx0, __shfl_xor(mx0, 16)); mx1 = fmaxf(mx1, __shfl_xor(mx1, 16));
    mx0 = fmaxf(mx0, __shfl_xor(mx0, 32)); mx1 = fmaxf(mx1, __shfl_xor(mx1, 32));
    float e0[4], e1[4];
#pragma unroll
    for (int i = 0; i < 4; i++) {
      e0[i] = __expf(dsc0[i] - mx0);
      e1[i] = __expf(dsc1[i] - mx1);
    }
    float se0 = e0[0] + e0[1] + e0[2] + e0[3];
    float se1 = e1[0] + e1[1] + e1[2] + e1[3];
    se0 += __shfl_xor(se0, 16); se1 += __shfl_xor(se1, 16);
    se0 += __shfl_xor(se0, 32); se1 += __shfl_xor(se1, 32);
    float inv0 = 1.0f / se0, inv1 = 1.0f / se1;
    float a0v[4], ar0[4], a1v[4], ar1[4];
#pragma unroll
    for (int i = 0; i < 4; i++) {
      a0v[i] = fmaf(e0[i], inv0, ATTN_EPS); ar0[i] = a0v[i] * rs0;
      a1v[i] = fmaf(e1[i], inv1, ATTN_EPS); ar1[i] = a1v[i] * rs1;
    }

    // ---- P accumulation (shared accumulators, row r then r+1) ----
#pragma unroll
    for (int j = 0; j < 16; j++) {
#pragma unroll
      for (int i = 0; i < 4; i++) {
        P[i][j] = fmaf(ar0[i], x0[j], P[i][j]);
        P[i][j] = fmaf(ar1[i], x1[j], P[i][j]);
      }
    }
#pragma unroll
    for (int i = 0; i < 4; i++) {
      Q[i] = fmaf(a0v[i], mrs0, Q[i]);
      Q[i] = fmaf(a1v[i], mrs1, Q[i]);
      Sa[i] += a0v[i];
      Sa[i] += a1v[i];
    }

    cA0 = pA0; cB0 = pB0; cC0 = pC0; cD0 = pD0;
    cA1 = pA1; cB1 = pB1; cC1 = pC1; cD1 = pD1;
  }

  // Two-stage cross-wave reduce in 64KB LDS (Uy = P - Q per slot/elem).
  int slot = wave & 3;
  if (wave < 4) {
#pragma unroll
    for (int i = 0; i < 4; i++) {
#pragma unroll
      for (int jq = 0; jq < 4; jq++) {
        float4 v4;
        v4.x = P[i][4 * jq + 0] - Q[i]; v4.y = P[i][4 * jq + 1] - Q[i];
        v4.z = P[i][4 * jq + 2] - Q[i]; v4.w = P[i][4 * jq + 3] - Q[i];
        *(float4*)&red[slot * 4096 + (4 * p + i) * 256 + g * 16 + jq * 4] = v4;
      }
    }
  }
  if (g == 0) {
#pragma unroll
    for (int i = 0; i < 4; i++) redS[wave * 16 + 4 * p + i] = Sa[i];
  }
  __syncthreads();
  if (wave >= 4) {
#pragma unroll
    for (int i = 0; i < 4; i++) {
#pragma unroll
      for (int jq = 0; jq < 4; jq++) {
        float4* dst = (float4*)&red[slot * 4096 + (4 * p + i) * 256 + g * 16 + jq * 4];
        float4 c = *dst;
        c.x += P[i][4 * jq + 0] - Q[i]; c.y += P[i][4 * jq + 1] - Q[i];
        c.z += P[i][4 * jq + 2] - Q[i]; c.w += P[i][4 * jq + 3] - Q[i];
        *dst = c;
      }
    }
  }
  __syncthreads();
  int slice = blockIdx.x & 63;
#pragma unroll
  for (int k = 0; k < 8; k++) {
    int idx = k * 512 + t;
    float v = red[idx] + red[4096 + idx] + red[8192 + idx] + red[12288 + idx];
    atomicAdd(&ws[WS_PARTU + (size_t)slice * 4096 + idx], v);
  }
  if (t < 16) {
    float sv = 0.f;
#pragma unroll
    for (int w = 0; w < 8; w++) sv += redS[w * 16 + t];
    atomicAdd(&ws[WS_PARTS + slice * 16 + t], sv);
  }
}

// =====================================================================
// K_red: reduce 64 atomic slices -> U[16][256], S[16]; self-zeros the
// slices for the next iteration (1MB input vs old 8MB).
// =====================================================================
__global__ __launch_bounds__(256) void k_red(float* __restrict__ ws)
{
  __shared__ __align__(16) float sAux[256];
  int bid = blockIdx.x, t = threadIdx.x;
  if (bid < 256) {
    int el = t & 15, wg = t >> 4;
    int e = bid * 16 + el;
    float acc = 0.f;
#pragma unroll
    for (int k = 0; k < 4; k++) {
      size_t idx = WS_PARTU + (size_t)(wg + k * 16) * 4096 + e;
      acc += ws[idx];
      ws[idx] = 0.f;
    }
    sAux[t] = acc;
    __syncthreads();
    if (t < 16) {
      float s = 0.f;
      for (int w = 0; w < 16; w++) s += sAux[w * 16 + t];
      ws[WS_U + bid * 16 + t] = s;
    }
  } else {
    int n = t & 15, wg = t >> 4;
    float acc = 0.f;
#pragma unroll
    for (int k = 0; k < 4; k++) {
      int idx = WS_PARTS + (wg + k * 16) * 16 + n;
      acc += ws[idx];
      ws[idx] = 0.f;
    }
    sAux[t] = acc;
    __syncthreads();
    if (t < 16) {
      float s = 0.f;
      for (int w = 0; w < 16; w++) s += sAux[w * 16 + t];
      ws[WS_S + t] = s;
    }
  }
}

// =====================================================================
// K_gxgh: bid<64:  gx[n][j] = W_ihv[j]·(g_in*(U[n]/S[n]) + be_in) + bgx[j]
//         bid>=64: gh[n][j] = W_hh[j]·slots_prev[n] + b_hh[j]
// =====================================================================
__global__ __launch_bounds__(256) void k_gxgh(
    const float* __restrict__ W_hh, const float* __restrict__ b_hh,
    const float* __restrict__ g_in, const float* __restrict__ be_in,
    float* __restrict__ ws)
{
  __shared__ __align__(16) float sU[16 * 260];
  __shared__ __align__(16) float sInv[16];
  int bid = blockIdx.x, t = threadIdx.x;
  bool isgx = bid < 64;
  if (isgx && t < 16) sInv[t] = 1.0f / ws[WS_S + t];
  __syncthreads();
  if (isgx) {
    float gi = g_in[t], bi = be_in[t];
    for (int n = 0; n < 16; n++)
      sU[n * 260 + t] = fmaf(gi * ws[WS_U + n * 256 + t], sInv[n], bi);
  } else {
    for (int n = 0; n < 16; n++)
      sU[n * 260 + t] = ws[WS_SLOTS + n * 256 + t];
  }
  __syncthreads();
  int jr = t >> 4, n = t & 15;
  if (jr < 12) {
    int j = (isgx ? bid : bid - 64) * 12 + jr;
    const float* srow = &sU[n * 260];
    const float* wrow = isgx ? (ws + WS_WIHV + j * 256) : (W_hh + j * 256);
    float acc = isgx ? ws[WS_BGX + j] : b_hh[j];
#pragma unroll 8
    for (int k = 0; k < 64; k++) {
      float4 w = *(const float4*)(wrow + k * 4);
      float4 s4 = *(const float4*)(srow + k * 4);
      acc = fmaf(w.x, s4.x, fmaf(w.y, s4.y, fmaf(w.z, s4.z, fmaf(w.w, s4.w, acc))));
    }
    if (isgx) ws[WS_GX + n * 768 + j] = acc;
    else      ws[WS_GH + n * 768 + j] = acc;
  }
}

// =====================================================================
// K_midh1: GRU gates -> slots_mid; LN(g_f,be_f); h1 = relu(lnf@W1.T + b1)
// =====================================================================
__global__ __launch_bounds__(256) void k_midh1(
    const float* __restrict__ W1, const float* __restrict__ b1,
    const float* __restrict__ g_f, const float* __restrict__ be_f,
    float* __restrict__ ws)
{
  __shared__ __align__(16) float sM[16 * 260];
  __shared__ __align__(16) float sAux[512];
  __shared__ __align__(16) float sStat[32];
  int bid = blockIdx.x, t = threadIdx.x;
  for (int n = 0; n < 16; n++) {
    float xr = ws[WS_GX + n * 768 + t],       hr = ws[WS_GH + n * 768 + t];
    float xz = ws[WS_GX + n * 768 + 256 + t], hz = ws[WS_GH + n * 768 + 256 + t];
    float xn = ws[WS_GX + n * 768 + 512 + t], hn = ws[WS_GH + n * 768 + 512 + t];
    float sp = ws[WS_SLOTS + n * 256 + t];
    float r = 1.f / (1.f + __expf(-(xr + hr)));
    float z = 1.f / (1.f + __expf(-(xz + hz)));
    float nn = tanhf(fmaf(r, hn, xn));
    float mid = fmaf(z, sp - nn, nn);
    sM[n * 260 + t] = mid;
    if (bid == 0) ws[WS_MID + n * 256 + t] = mid;
  }
  __syncthreads();
  { int n = t >> 4, c = t & 15;
    float s1 = 0.f, s2 = 0.f;
    for (int k = 0; k < 16; k++) {
      float x = sM[n * 260 + c * 16 + k];
      s1 += x; s2 = fmaf(x, x, s2);
    }
    sAux[n * 16 + c] = s1; sAux[256 + n * 16 + c] = s2; }
  __syncthreads();
  if (t < 16) {
    float s1 = 0.f, s2 = 0.f;
    for (int c = 0; c < 16; c++) { s1 += sAux[t * 16 + c]; s2 += sAux[256 + t * 16 + c]; }
    float m = s1 * (1.f / 256.f);
    float v = fmaxf(fmaf(-m, m, s2 * (1.f / 256.f)), 0.f);
    sStat[t] = m; sStat[16 + t] = rsqrtf(v + LN_EPS);
  }
  __syncthreads();
  { float gf = g_f[t], bf = be_f[t];
    for (int n = 0; n < 16; n++) {
      float m = sStat[n], rs = sStat[16 + n];
      sM[n * 260 + t] = fmaf((sM[n * 260 + t] - m) * rs, gf, bf);
    } }
  __syncthreads();
  int jr = t >> 6, n = (t >> 2) & 15, ks = t & 3;
  int j = bid * 4 + jr;
  const float* wrow = W1 + j * 256 + ks * 64;
  const float* srow = &sM[n * 260 + ks * 64];
  float acc = 0.f;
#pragma unroll
  for (int k = 0; k < 16; k++) {
    float4 w = *(const float4*)(wrow + k * 4);
    float4 s4 = *(const float4*)(srow + k * 4);
    acc = fmaf(w.x, s4.x, fmaf(w.y, s4.y, fmaf(w.z, s4.z, fmaf(w.w, s4.w, acc))));
  }
  sAux[t] = acc;
  __syncthreads();
  if (t < 64) {
    int jr2 = t >> 4, n2 = t & 15;
    int j2 = bid * 4 + jr2;
    int b = jr2 * 64 + n2 * 4;
    float s = sAux[b] + sAux[b + 1] + sAux[b + 2] + sAux[b + 3] + b1[j2];
    ws[WS_H1 + n2 * 256 + j2] = fmaxf(s, 0.f);
  }
}

// =====================================================================
// K_ffnew: ff = h1@W2.T + b2;  slots_new = slots_mid + ff -> ws.slots, d_out
// =====================================================================
__global__ __launch_bounds__(256) void k_ffnew(
    const float* __restrict__ W2, const float* __restrict__ b2v,
    float* __restrict__ out, float* __restrict__ ws)
{
  __shared__ __align__(16) float sH[16 * 260];
  __shared__ __align__(16) float sAux[256];
  int bid = blockIdx.x, t = threadIdx.x;
  for (int n = 0; n < 16; n++)
    sH[n * 260 + t] = ws[WS_H1 + n * 256 + t];
  __syncthreads();
  int dr = t >> 6, n = (t >> 2) & 15, ks = t & 3;
  int d = bid * 4 + dr;
  const float* wrow = W2 + d * 256 + ks * 64;
  const float* srow = &sH[n * 260 + ks * 64];
  float acc = 0.f;
#pragma unroll
  for (int k = 0; k < 16; k++) {
    float4 w = *(const float4*)(wrow + k * 4);
    float4 s4 = *(const float4*)(srow + k * 4);
    acc = fmaf(w.x, s4.x, fmaf(w.y, s4.y, fmaf(w.z, s4.z, fmaf(w.w, s4.w, acc))));
  }
  sAux[t] = acc;
  __syncthreads();
  if (t < 64) {
    int dr2 = t >> 4, n2 = t & 15;
    int d2 = bid * 4 + dr2;
    int b = dr2 * 64 + n2 * 4;
    float s = sAux[b] + sAux[b + 1] + sAux[b + 2] + sAux[b + 3]
            + b2v[d2] + ws[WS_MID + n2 * 256 + d2];
    ws[WS_SLOTS + n2 * 256 + d2] = s;
    out[n2 * 256 + d2] = s;
  }
}

// =====================================================================
extern "C" void kernel_launch(void* const* d_in, const int* in_sizes, int n_in,
                              void* d_out, int out_size, void* d_ws, size_t ws_size,
                              hipStream_t stream)
{
  (void)in_sizes; (void)n_in; (void)out_size; (void)ws_size;
  const float* inputs = (const float*)d_in[0];
  const float* noise  = (const float*)d_in[1];
  const float* mu     = (const float*)d_in[2];
  const float* sigma  = (const float*)d_in[3];
  const float* Wq     = (const float*)d_in[4];
  const float* bq     = (const float*)d_in[5];
  const float* Wk     = (const float*)d_in[6];
  const float* bk     = (const float*)d_in[7];
  const float* Wv     = (const float*)d_in[8];
  const float* bv     = (const float*)d_in[9];
  const float* W_ih   = (const float*)d_in[10];
  const float* W_hh   = (const float*)d_in[11];
  const float* b_ih   = (const float*)d_in[12];
  const float* b_hh   = (const float*)d_in[13];
  const float* W1     = (const float*)d_in[14];
  const float* b1     = (const float*)d_in[15];
  const float* W2     = (const float*)d_in[16];
  const float* b2     = (const float*)d_in[17];
  const float* g_in   = (const float*)d_in[18];
  const float* be_in  = (const float*)d_in[19];
  const float* g_s    = (const float*)d_in[20];
  const float* be_s   = (const float*)d_in[21];
  const float* g_f    = (const float*)d_in[22];
  const float* be_f   = (const float*)d_in[23];
  float* ws = (float*)d_ws;
  float* out = (float*)d_out;

  hipLaunchKernelGGL(k_pre1, dim3(257), dim3(256), 0, stream,
                     Wq, bq, Wk, bk, Wv, bv, W_ih, b_ih, g_in, be_in, ws);
  hipLaunchKernelGGL(k_qkg, dim3(65), dim3(256), 0, stream,
                     noise, mu, sigma, g_s, be_s, ws, 1);
  for (int it = 0; it < 3; it++) {
    hipLaunchKernelGGL(k_big, dim3(BIG_BLOCKS), dim3(BIG_THREADS), 0, stream, inputs, ws);
    hipLaunchKernelGGL(k_red, dim3(257), dim3(256), 0, stream, ws);
    hipLaunchKernelGGL(k_gxgh, dim3(128), dim3(256), 0, stream,
                       W_hh, b_hh, g_in, be_in, ws);
    hipLaunchKernelGGL(k_midh1, dim3(64), dim3(256), 0, stream,
                       W1, b1, g_f, be_f, ws);
    hipLaunchKernelGGL(k_ffnew, dim3(64), dim3(256), 0, stream,
                       W2, b2, out, ws);
    if (it < 2)
      hipLaunchKernelGGL(k_qkg, dim3(65), dim3(256), 0, stream,
                         noise, mu, sigma, g_s, be_s, ws, 0);
  }
}

// Round 10
// 553.122 us; speedup vs baseline: 1.2189x; 1.0079x over previous
//
#include <hip/hip_runtime.h>
#include <stdint.h>

#define B_ROWS 131072
#define SCALE 0.0625f
#define LN_EPS 1e-5f
#define ATTN_EPS 1e-8f

#define BIG_BLOCKS 512
#define BIG_THREADS 512
#define ROWS_PER_BLOCK (B_ROWS / BIG_BLOCKS)   // 256
#define ROWS_PER_WAVE  (ROWS_PER_BLOCK / 8)    // 32 (8 waves/block)
#define NSLICE 8                               // 8 atomic accumulation slices

// ---- workspace layout (float offsets) ----
#define WS_PARTU 0
#define WS_RS    (WS_PARTU + 64*4096)            // 262144: rs per row (iter-invariant LN stats)
#define WS_MRS   (WS_RS + B_ROWS)                // 393216: mean*rs per row
#define WS_PARTS (WS_PARTU + 512*4096)           // 2097152 (only 8*16 used)
#define WS_U     (WS_PARTS + 512*16)             // 2105344 (unused)
#define WS_S     (WS_U + 4096)                   // 2109440 (unused)
#define WS_SLOTS (WS_S + 64)                     // 2109504
#define WS_MID   (WS_SLOTS + 4096)               // 2113600
#define WS_GX    (WS_MID + 4096)                 // 2117696
#define WS_GH    (WS_GX + 12288)                 // 2129984
#define WS_H1    (WS_GH + 12288)                 // 2142272
#define WS_QKG   (WS_H1 + 4096)                  // 2146368
#define WS_QB    (WS_QKG + 4096)                 // 2150464
#define WS_WIHV  (WS_QB + 64)                    // 2150528
#define WS_BGX   (WS_WIHV + 196608)              // 2347136
#define WS_WQKG  (WS_BGX + 768)                  // 2347904
#define WS_U2G   (WS_WQKG + 65536)               // 2413440
#define WS_U1    (WS_U2G + 256)                  // 2413696
#define WS_C1    (WS_U1 + 256)                   // 2413952

// =====================================================================
// K_pre1: weight compositions, 257 blocks (R3 restructure, ~10us)
// + zero the 8-slice PARTU/PARTS accumulators (re-zeroed every replay).
// =====================================================================
__global__ __launch_bounds__(256) void k_pre1(
    const float* __restrict__ Wq, const float* __restrict__ bq,
    const float* __restrict__ Wk, const float* __restrict__ bk,
    const float* __restrict__ Wv, const float* __restrict__ bv,
    const float* __restrict__ W_ih, const float* __restrict__ b_ih,
    const float* __restrict__ g_in, const float* __restrict__ be_in,
    float* __restrict__ ws)
{
  int bid = blockIdx.x, t = threadIdx.x;
  int wave = t >> 6, lane = t & 63;
  // zero atomic accumulators: blocks 0..31 cover 8*4096; block 256 PARTS
  if (bid < 32) {
#pragma unroll
    for (int q = 0; q < 4; q++)
      ws[WS_PARTU + bid * 1024 + q * 256 + t] = 0.f;
  } else if (bid == 256) {
    if (t < 128) ws[WS_PARTS + t] = 0.f;
  }
  if (bid < 192) {
    __shared__ __align__(16) float sW[4 * 256];
    __shared__ __align__(16) float sBv[256];
    int j0 = bid * 4;
#pragma unroll
    for (int r = 0; r < 4; r++) sW[r * 256 + t] = W_ih[(j0 + r) * 256 + t];
    sBv[t] = bv[t];
    __syncthreads();
    int d = t;
    float a0 = 0.f, a1 = 0.f, a2 = 0.f, a3 = 0.f;
#pragma unroll 8
    for (int dd = 0; dd < 256; dd++) {
      float v = Wv[dd * 256 + d];
      a0 = fmaf(sW[0 * 256 + dd], v, a0);
      a1 = fmaf(sW[1 * 256 + dd], v, a1);
      a2 = fmaf(sW[2 * 256 + dd], v, a2);
      a3 = fmaf(sW[3 * 256 + dd], v, a3);
    }
    ws[WS_WIHV + (j0 + 0) * 256 + d] = a0;
    ws[WS_WIHV + (j0 + 1) * 256 + d] = a1;
    ws[WS_WIHV + (j0 + 2) * 256 + d] = a2;
    ws[WS_WIHV + (j0 + 3) * 256 + d] = a3;
    float s = 0.f;
#pragma unroll
    for (int q = 0; q < 4; q++) {
      int idx = lane * 4 + q;
      s = fmaf(sW[wave * 256 + idx], sBv[idx], s);
    }
#pragma unroll
    for (int m = 1; m <= 32; m <<= 1) s += __shfl_xor(s, m);
    if (lane == 0) ws[WS_BGX + j0 + wave] = b_ih[j0 + wave] + s;
  } else if (bid < 256) {
    __shared__ __align__(16) float sKc[4 * 256];
    __shared__ __align__(16) float sBq[256];
    int c0 = (bid - 192) * 4;
#pragma unroll
    for (int r = 0; r < 4; r++) sKc[r * 256 + t] = Wk[t * 256 + c0 + r];
    sBq[t] = bq[t];
    __syncthreads();
    int d = t;
    float a0 = 0.f, a1 = 0.f, a2 = 0.f, a3 = 0.f;
#pragma unroll 8
    for (int i = 0; i < 256; i++) {
      float wq = Wq[i * 256 + d];
      a0 = fmaf(wq, sKc[0 * 256 + i], a0);
      a1 = fmaf(wq, sKc[1 * 256 + i], a1);
      a2 = fmaf(wq, sKc[2 * 256 + i], a2);
      a3 = fmaf(wq, sKc[3 * 256 + i], a3);
    }
    ws[WS_WQKG + (c0 + 0) * 256 + d] = SCALE * g_in[c0 + 0] * a0;
    ws[WS_WQKG + (c0 + 1) * 256 + d] = SCALE * g_in[c0 + 1] * a1;
    ws[WS_WQKG + (c0 + 2) * 256 + d] = SCALE * g_in[c0 + 2] * a2;
    ws[WS_WQKG + (c0 + 3) * 256 + d] = SCALE * g_in[c0 + 3] * a3;
    float s = 0.f;
#pragma unroll
    for (int q = 0; q < 4; q++) {
      int idx = lane * 4 + q;
      s = fmaf(sBq[idx], sKc[wave * 256 + idx], s);
    }
#pragma unroll
    for (int m = 1; m <= 32; m <<= 1) s += __shfl_xor(s, m);
    if (lane == 0) ws[WS_U2G + c0 + wave] = SCALE * g_in[c0 + wave] * s;
  } else {
    __shared__ __align__(16) float sBe[256];
    __shared__ __align__(16) float sT2[256];
    sBe[t] = be_in[t];
    __syncthreads();
    float a = 0.f;
#pragma unroll 8
    for (int dp = 0; dp < 256; dp += 4) {
      float4 w = *(const float4*)(Wk + t * 256 + dp);
      a = fmaf(w.x, sBe[dp], fmaf(w.y, sBe[dp + 1],
          fmaf(w.z, sBe[dp + 2], fmaf(w.w, sBe[dp + 3], a))));
    }
    sT2[t] = a + bk[t];
    __syncthreads();
    float u = 0.f;
#pragma unroll 8
    for (int i = 0; i < 256; i++)
      u = fmaf(Wq[i * 256 + t], sT2[i], u);
    ws[WS_U1 + t] = u;
    if (wave == 0) {
      float s = 0.f;
#pragma unroll
      for (int q = 0; q < 4; q++) {
        int idx = lane * 4 + q;
        s = fmaf(bq[idx], sT2[idx], s);
      }
#pragma unroll
      for (int m = 1; m <= 32; m <<= 1) s += __shfl_xor(s, m);
      if (lane == 0) ws[WS_C1] = s;
    }
  }
}

// =====================================================================
// K_qkg: s = LN(slots); qkg/qb. init: slots = mu + sigma*noise.
// =====================================================================
__global__ __launch_bounds__(256) void k_qkg(
    const float* __restrict__ noise, const float* __restrict__ mu,
    const float* __restrict__ sigma, const float* __restrict__ g_s,
    const float* __restrict__ be_s, float* __restrict__ ws, int init)
{
  __shared__ __align__(16) float sS[16 * 260];
  __shared__ __align__(16) float sAux[512];
  __shared__ __align__(16) float sStat[32];
  int bid = blockIdx.x, t = threadIdx.x;
  for (int n = 0; n < 16; n++) {
    float v;
    if (init) v = fmaf(sigma[t], noise[n * 256 + t], mu[t]);
    else      v = ws[WS_SLOTS + n * 256 + t];
    sS[n * 260 + t] = v;
    if (init && bid == 0) ws[WS_SLOTS + n * 256 + t] = v;
  }
  __syncthreads();
  { int n = t >> 4, c = t & 15;
    float s1 = 0.f, s2 = 0.f;
    for (int k = 0; k < 16; k++) {
      float x = sS[n * 260 + c * 16 + k];
      s1 += x; s2 = fmaf(x, x, s2);
    }
    sAux[n * 16 + c] = s1; sAux[256 + n * 16 + c] = s2; }
  __syncthreads();
  if (t < 16) {
    float s1 = 0.f, s2 = 0.f;
    for (int c = 0; c < 16; c++) { s1 += sAux[t * 16 + c]; s2 += sAux[256 + t * 16 + c]; }
    float m = s1 * (1.f / 256.f);
    float v = fmaxf(fmaf(-m, m, s2 * (1.f / 256.f)), 0.f);
    sStat[t] = m; sStat[16 + t] = rsqrtf(v + LN_EPS);
  }
  __syncthreads();
  { float gs = g_s[t], bs = be_s[t];
    for (int n = 0; n < 16; n++) {
      float m = sStat[n], rs = sStat[16 + n];
      sS[n * 260 + t] = fmaf((sS[n * 260 + t] - m) * rs, gs, bs);
    } }
  __syncthreads();
  if (bid < 64) {
    int cr = t >> 6, n = (t >> 2) & 15, ks = t & 3;
    int c = bid * 4 + cr;
    const float* wrow = ws + WS_WQKG + c * 256 + ks * 64;
    const float* srow = &sS[n * 260 + ks * 64];
    float acc = 0.f;
#pragma unroll
    for (int i = 0; i < 16; i++) {
      float4 w = *(const float4*)(wrow + i * 4);
      float4 s4 = *(const float4*)(srow + i * 4);
      acc = fmaf(w.x, s4.x, fmaf(w.y, s4.y, fmaf(w.z, s4.z, fmaf(w.w, s4.w, acc))));
    }
    sAux[t] = acc;
    __syncthreads();
    if (t < 64) {
      int cr2 = t >> 4, n2 = t & 15;
      int c2 = bid * 4 + cr2;
      int b = cr2 * 64 + n2 * 4;
      float s = sAux[b] + sAux[b + 1] + sAux[b + 2] + sAux[b + 3];
      ws[WS_QKG + n2 * 256 + c2] = s + ws[WS_U2G + c2];
    }
  } else {
    int n = t >> 4, ks = t & 15;
    float acc = 0.f;
    for (int k = 0; k < 16; k++)
      acc = fmaf(sS[n * 260 + ks * 16 + k], ws[WS_U1 + ks * 16 + k], acc);
    sAux[t] = acc;
    __syncthreads();
    if (t < 16) {
      float s = 0.f;
      for (int k = 0; k < 16; k++) s += sAux[t * 16 + k];
      ws[WS_QB + t] = SCALE * (s + ws[WS_C1]);
    }
  }
}

// =====================================================================
// K_big: pair-ILP + distance-1 prefetch (R5/R7 proven, 98us).
// NEW: LN stats (mean,rs) are iteration-invariant — iter 0 computes and
// stores rs/mrs per row (1MB); iters 1,2 load them (wave-uniform dword,
// issued with the prefetch) and skip the 4 stats chains + 16 shfl in
// the butterfly (~12% fewer instructions). Bit-identical numerics.
// Epilogue: atomicAdd into 8 shared slices (slice = bid & 7).
// =====================================================================
__global__ __launch_bounds__(512, 2) void k_big(
    const float* __restrict__ X, float* __restrict__ ws, int it)
{
  __shared__ __align__(16) float red[4 * 4096];   // 64 KB
  __shared__ __align__(16) float redS[128];       // 8 waves x 16
  int t = threadIdx.x;
  int wave = t >> 6, lane = t & 63;
  int p = lane >> 4, g = lane & 15;

  const float* qkg = ws + WS_QKG;
  float qw[4][16];
  float qs[4];
#pragma unroll
  for (int i = 0; i < 4; i++) {
    const float* rp = qkg + (4 * p + i) * 256 + g * 16;
#pragma unroll
    for (int jq = 0; jq < 4; jq++) {
      float4 v4 = *(const float4*)(rp + 4 * jq);
      qw[i][4 * jq + 0] = v4.x; qw[i][4 * jq + 1] = v4.y;
      qw[i][4 * jq + 2] = v4.z; qw[i][4 * jq + 3] = v4.w;
    }
    float s = 0.f;
#pragma unroll
    for (int j = 0; j < 16; j++) s += qw[i][j];
    qs[i] = s;
  }
#pragma unroll
  for (int m = 1; m <= 8; m <<= 1) {
#pragma unroll
    for (int i = 0; i < 4; i++) qs[i] += __shfl_xor(qs[i], m);
  }
  float qb0[4];
  {
    float4 q4 = *(const float4*)(ws + WS_QB + 4 * p);
    qb0[0] = q4.x; qb0[1] = q4.y; qb0[2] = q4.z; qb0[3] = q4.w;
  }

  float P[4][16];
#pragma unroll
  for (int i = 0; i < 4; i++)
#pragma unroll
    for (int j = 0; j < 16; j++) P[i][j] = 0.f;
  float Q[4] = {0.f, 0.f, 0.f, 0.f};
  float Sa[4] = {0.f, 0.f, 0.f, 0.f};

  size_t rowbase = (size_t)blockIdx.x * ROWS_PER_BLOCK + (size_t)wave * ROWS_PER_WAVE;
  const float* base = X + rowbase * 256 + g * 16;

  float4 cA0 = *(const float4*)(base + 0);
  float4 cB0 = *(const float4*)(base + 4);
  float4 cC0 = *(const float4*)(base + 8);
  float4 cD0 = *(const float4*)(base + 12);
  float4 cA1 = *(const float4*)(base + 256);
  float4 cB1 = *(const float4*)(base + 260);
  float4 cC1 = *(const float4*)(base + 264);
  float4 cD1 = *(const float4*)(base + 268);

#pragma unroll 1
  for (int r = 0; r < ROWS_PER_WAVE; r += 2) {
    const float* nx = base + (size_t)((r + 2 < ROWS_PER_WAVE) ? (r + 2) : 0) * 256;
    float4 pA0 = *(const float4*)(nx + 0);
    float4 pB0 = *(const float4*)(nx + 4);
    float4 pC0 = *(const float4*)(nx + 8);
    float4 pD0 = *(const float4*)(nx + 12);
    float4 pA1 = *(const float4*)(nx + 256);
    float4 pB1 = *(const float4*)(nx + 260);
    float4 pC1 = *(const float4*)(nx + 264);
    float4 pD1 = *(const float4*)(nx + 268);

    size_t row = rowbase + r;
    float rsL0 = 0.f, mrsL0 = 0.f, rsL1 = 0.f, mrsL1 = 0.f;
    if (it != 0) {
      // wave-uniform loads, issued early to hide L2 latency under the
      // partial loop + butterfly
      rsL0 = ws[WS_RS + row];      mrsL0 = ws[WS_MRS + row];
      rsL1 = ws[WS_RS + row + 1];  mrsL1 = ws[WS_MRS + row + 1];
    }

    float x0[16], x1[16];
    x0[0] = cA0.x; x0[1] = cA0.y; x0[2] = cA0.z; x0[3] = cA0.w;
    x0[4] = cB0.x; x0[5] = cB0.y; x0[6] = cB0.z; x0[7] = cB0.w;
    x0[8] = cC0.x; x0[9] = cC0.y; x0[10] = cC0.z; x0[11] = cC0.w;
    x0[12] = cD0.x; x0[13] = cD0.y; x0[14] = cD0.z; x0[15] = cD0.w;
    x1[0] = cA1.x; x1[1] = cA1.y; x1[2] = cA1.z; x1[3] = cA1.w;
    x1[4] = cB1.x; x1[5] = cB1.y; x1[6] = cB1.z; x1[7] = cB1.w;
    x1[8] = cC1.x; x1[9] = cC1.y; x1[10] = cC1.z; x1[11] = cC1.w;
    x1[12] = cD1.x; x1[13] = cD1.y; x1[14] = cD1.z; x1[15] = cD1.w;

    // ---- partial sums: dots always; stats only on iter 0 ----
    float s10 = 0.f, s20 = 0.f, s11 = 0.f, s21 = 0.f;
    float d0[4] = {0.f, 0.f, 0.f, 0.f};
    float d1[4] = {0.f, 0.f, 0.f, 0.f};
    if (it == 0) {
#pragma unroll
      for (int j = 0; j < 16; j++) {
        s10 += x0[j]; s20 = fmaf(x0[j], x0[j], s20);
        s11 += x1[j]; s21 = fmaf(x1[j], x1[j], s21);
#pragma unroll
        for (int i = 0; i < 4; i++) {
          d0[i] = fmaf(qw[i][j], x0[j], d0[i]);
          d1[i] = fmaf(qw[i][j], x1[j], d1[i]);
        }
      }
#pragma unroll
      for (int m = 1; m <= 8; m <<= 1) {
        s10 += __shfl_xor(s10, m); s11 += __shfl_xor(s11, m);
        s20 += __shfl_xor(s20, m); s21 += __shfl_xor(s21, m);
#pragma unroll
        for (int i = 0; i < 4; i++) {
          d0[i] += __shfl_xor(d0[i], m);
          d1[i] += __shfl_xor(d1[i], m);
        }
      }
    } else {
#pragma unroll
      for (int j = 0; j < 16; j++) {
#pragma unroll
        for (int i = 0; i < 4; i++) {
          d0[i] = fmaf(qw[i][j], x0[j], d0[i]);
          d1[i] = fmaf(qw[i][j], x1[j], d1[i]);
        }
      }
#pragma unroll
      for (int m = 1; m <= 8; m <<= 1) {
#pragma unroll
        for (int i = 0; i < 4; i++) {
          d0[i] += __shfl_xor(d0[i], m);
          d1[i] += __shfl_xor(d1[i], m);
        }
      }
    }

    float rs0, rs1, mrs0, mrs1;
    if (it == 0) {
      float mean0 = s10 * (1.f / 256.f), mean1 = s11 * (1.f / 256.f);
      float var0 = fmaxf(fmaf(-mean0, mean0, s20 * (1.f / 256.f)), 0.f);
      float var1 = fmaxf(fmaf(-mean1, mean1, s21 * (1.f / 256.f)), 0.f);
      rs0 = rsqrtf(var0 + LN_EPS); rs1 = rsqrtf(var1 + LN_EPS);
      mrs0 = mean0 * rs0; mrs1 = mean1 * rs1;
      if (lane == 0) {
        ws[WS_RS + row] = rs0;      ws[WS_MRS + row] = mrs0;
        ws[WS_RS + row + 1] = rs1;  ws[WS_MRS + row + 1] = mrs1;
      }
    } else {
      rs0 = rsL0; mrs0 = mrsL0; rs1 = rsL1; mrs1 = mrsL1;
    }

    float dsc0[4], dsc1[4];
#pragma unroll
    for (int i = 0; i < 4; i++) {
      dsc0[i] = fmaf(rs0, d0[i], fmaf(-mrs0, qs[i], qb0[i]));
      dsc1[i] = fmaf(rs1, d1[i], fmaf(-mrs1, qs[i], qb0[i]));
    }

    // ---- softmax, both rows interleaved ----
    float mx0 = fmaxf(fmaxf(dsc0[0], dsc0[1]), fmaxf(dsc0[2], dsc0[3]));
    float mx1 = fmaxf(fmaxf(dsc1[0], dsc1[1]), fmaxf(dsc1[2], dsc1[3]));
    mx0 = fmaxf(mx0, __shfl_xor(mx0, 16)); mx1 = fmaxf(mx1, __shfl_xor(mx1, 16));
    mx0 = fmaxf(mx0, __shfl_xor(mx0, 32)); mx1 = fmaxf(mx1, __shfl_xor(mx1, 32));
    float e0[4], e1[4];
#pragma unroll
    for (int i = 0; i < 4; i++) {
      e0[i] = __expf(dsc0[i] - mx0);
      e1[i] = __expf(dsc1[i] - mx1);
    }
    float se0 = e0[0] + e0[1] + e0[2] + e0[3];
    float se1 = e1[0] + e1[1] + e1[2] + e1[3];
    se0 += __shfl_xor(se0, 16); se1 += __shfl_xor(se1, 16);
    se0 += __shfl_xor(se0, 32); se1 += __shfl_xor(se1, 32);
    float inv0 = 1.0f / se0, inv1 = 1.0f / se1;
    float a0v[4], ar0[4], a1v[4], ar1[4];
#pragma unroll
    for (int i = 0; i < 4; i++) {
      a0v[i] = fmaf(e0[i], inv0, ATTN_EPS); ar0[i] = a0v[i] * rs0;
      a1v[i] = fmaf(e1[i], inv1, ATTN_EPS); ar1[i] = a1v[i] * rs1;
    }

    // ---- P accumulation (shared accumulators, row r then r+1) ----
#pragma unroll
    for (int j = 0; j < 16; j++) {
#pragma unroll
      for (int i = 0; i < 4; i++) {
        P[i][j] = fmaf(ar0[i], x0[j], P[i][j]);
        P[i][j] = fmaf(ar1[i], x1[j], P[i][j]);
      }
    }
#pragma unroll
    for (int i = 0; i < 4; i++) {
      Q[i] = fmaf(a0v[i], mrs0, Q[i]);
      Q[i] = fmaf(a1v[i], mrs1, Q[i]);
      Sa[i] += a0v[i];
      Sa[i] += a1v[i];
    }

    cA0 = pA0; cB0 = pB0; cC0 = pC0; cD0 = pD0;
    cA1 = pA1; cB1 = pB1; cC1 = pC1; cD1 = pD1;
  }

  // Two-stage cross-wave reduce in 64KB LDS (Uy = P - Q per slot/elem).
  int slot = wave & 3;
  if (wave < 4) {
#pragma unroll
    for (int i = 0; i < 4; i++) {
#pragma unroll
      for (int jq = 0; jq < 4; jq++) {
        float4 v4;
        v4.x = P[i][4 * jq + 0] - Q[i]; v4.y = P[i][4 * jq + 1] - Q[i];
        v4.z = P[i][4 * jq + 2] - Q[i]; v4.w = P[i][4 * jq + 3] - Q[i];
        *(float4*)&red[slot * 4096 + (4 * p + i) * 256 + g * 16 + jq * 4] = v4;
      }
    }
  }
  if (g == 0) {
#pragma unroll
    for (int i = 0; i < 4; i++) redS[wave * 16 + 4 * p + i] = Sa[i];
  }
  __syncthreads();
  if (wave >= 4) {
#pragma unroll
    for (int i = 0; i < 4; i++) {
#pragma unroll
      for (int jq = 0; jq < 4; jq++) {
        float4* dst = (float4*)&red[slot * 4096 + (4 * p + i) * 256 + g * 16 + jq * 4];
        float4 c = *dst;
        c.x += P[i][4 * jq + 0] - Q[i]; c.y += P[i][4 * jq + 1] - Q[i];
        c.z += P[i][4 * jq + 2] - Q[i]; c.w += P[i][4 * jq + 3] - Q[i];
        *dst = c;
      }
    }
  }
  __syncthreads();
  int slice = blockIdx.x & 7;
#pragma unroll
  for (int k = 0; k < 8; k++) {
    int idx = k * 512 + t;
    float v = red[idx] + red[4096 + idx] + red[8192 + idx] + red[12288 + idx];
    atomicAdd(&ws[WS_PARTU + (size_t)slice * 4096 + idx], v);
  }
  if (t < 16) {
    float sv = 0.f;
#pragma unroll
    for (int w = 0; w < 8; w++) sv += redS[w * 16 + t];
    atomicAdd(&ws[WS_PARTS + slice * 16 + t], sv);
  }
}

// =====================================================================
// K_gxgh: k_red is GONE — gx blocks inline-reduce the 8 L2-resident
// PARTU slices (128KB) and PARTS directly.
// bid<64:  gx[n][j] = W_ihv[j]·(g_in*(U[n]/S[n]) + be_in) + bgx[j]
// bid>=64: gh[n][j] = W_hh[j]·slots_prev[n] + b_hh[j]
// =====================================================================
__global__ __launch_bounds__(256) void k_gxgh(
    const float* __restrict__ W_hh, const float* __restrict__ b_hh,
    const float* __restrict__ g_in, const float* __restrict__ be_in,
    float* __restrict__ ws)
{
  __shared__ __align__(16) float sU[16 * 260];
  __shared__ __align__(16) float sInv[16];
  int bid = blockIdx.x, t = threadIdx.x;
  bool isgx = bid < 64;
  if (isgx && t < 16) {
    float s = 0.f;
#pragma unroll
    for (int sl = 0; sl < NSLICE; sl++) s += ws[WS_PARTS + sl * 16 + t];
    sInv[t] = 1.0f / s;
  }
  __syncthreads();
  if (isgx) {
    float gi = g_in[t], bi = be_in[t];
    for (int n = 0; n < 16; n++) {
      float acc = 0.f;
#pragma unroll
      for (int sl = 0; sl < NSLICE; sl++)
        acc += ws[WS_PARTU + (size_t)sl * 4096 + n * 256 + t];
      sU[n * 260 + t] = fmaf(gi * acc, sInv[n], bi);
    }
  } else {
    for (int n = 0; n < 16; n++)
      sU[n * 260 + t] = ws[WS_SLOTS + n * 256 + t];
  }
  __syncthreads();
  int jr = t >> 4, n = t & 15;
  if (jr < 12) {
    int j = (isgx ? bid : bid - 64) * 12 + jr;
    const float* srow = &sU[n * 260];
    const float* wrow = isgx ? (ws + WS_WIHV + j * 256) : (W_hh + j * 256);
    float acc = isgx ? ws[WS_BGX + j] : b_hh[j];
#pragma unroll 8
    for (int k = 0; k < 64; k++) {
      float4 w = *(const float4*)(wrow + k * 4);
      float4 s4 = *(const float4*)(srow + k * 4);
      acc = fmaf(w.x, s4.x, fmaf(w.y, s4.y, fmaf(w.z, s4.z, fmaf(w.w, s4.w, acc))));
    }
    if (isgx) ws[WS_GX + n * 768 + j] = acc;
    else      ws[WS_GH + n * 768 + j] = acc;
  }
}

// =====================================================================
// K_midh1: GRU gates -> slots_mid; LN(g_f,be_f); h1 = relu(lnf@W1.T + b1)
// + zeroes the 8 PARTU/PARTS slices for the next iteration's k_big
// (runs after k_gxgh consumed them, before the next k_big).
// =====================================================================
__global__ __launch_bounds__(256) void k_midh1(
    const float* __restrict__ W1, const float* __restrict__ b1,
    const float* __restrict__ g_f, const float* __restrict__ be_f,
    float* __restrict__ ws)
{
  __shared__ __align__(16) float sM[16 * 260];
  __shared__ __align__(16) float sAux[512];
  __shared__ __align__(16) float sStat[32];
  int bid = blockIdx.x, t = threadIdx.x;
  {
    int gid = bid * 256 + t;               // 0..16383
    ws[WS_PARTU + gid] = 0.f;
    ws[WS_PARTU + 16384 + gid] = 0.f;      // 32768 = 8 slices x 4096
    if (gid < 128) ws[WS_PARTS + gid] = 0.f;
  }
  for (int n = 0; n < 16; n++) {
    float xr = ws[WS_GX + n * 768 + t],       hr = ws[WS_GH + n * 768 + t];
    float xz = ws[WS_GX + n * 768 + 256 + t], hz = ws[WS_GH + n * 768 + 256 + t];
    float xn = ws[WS_GX + n * 768 + 512 + t], hn = ws[WS_GH + n * 768 + 512 + t];
    float sp = ws[WS_SLOTS + n * 256 + t];
    float r = 1.f / (1.f + __expf(-(xr + hr)));
    float z = 1.f / (1.f + __expf(-(xz + hz)));
    float nn = tanhf(fmaf(r, hn, xn));
    float mid = fmaf(z, sp - nn, nn);
    sM[n * 260 + t] = mid;
    if (bid == 0) ws[WS_MID + n * 256 + t] = mid;
  }
  __syncthreads();
  { int n = t >> 4, c = t & 15;
    float s1 = 0.f, s2 = 0.f;
    for (int k = 0; k < 16; k++) {
      float x = sM[n * 260 + c * 16 + k];
      s1 += x; s2 = fmaf(x, x, s2);
    }
    sAux[n * 16 + c] = s1; sAux[256 + n * 16 + c] = s2; }
  __syncthreads();
  if (t < 16) {
    float s1 = 0.f, s2 = 0.f;
    for (int c = 0; c < 16; c++) { s1 += sAux[t * 16 + c]; s2 += sAux[256 + t * 16 + c]; }
    float m = s1 * (1.f / 256.f);
    float v = fmaxf(fmaf(-m, m, s2 * (1.f / 256.f)), 0.f);
    sStat[t] = m; sStat[16 + t] = rsqrtf(v + LN_EPS);
  }
  __syncthreads();
  { float gf = g_f[t], bf = be_f[t];
    for (int n = 0; n < 16; n++) {
      float m = sStat[n], rs = sStat[16 + n];
      sM[n * 260 + t] = fmaf((sM[n * 260 + t] - m) * rs, gf, bf);
    } }
  __syncthreads();
  int jr = t >> 6, n = (t >> 2) & 15, ks = t & 3;
  int j = bid * 4 + jr;
  const float* wrow = W1 + j * 256 + ks * 64;
  const float* srow = &sM[n * 260 + ks * 64];
  float acc = 0.f;
#pragma unroll
  for (int k = 0; k < 16; k++) {
    float4 w = *(const float4*)(wrow + k * 4);
    float4 s4 = *(const float4*)(srow + k * 4);
    acc = fmaf(w.x, s4.x, fmaf(w.y, s4.y, fmaf(w.z, s4.z, fmaf(w.w, s4.w, acc))));
  }
  sAux[t] = acc;
  __syncthreads();
  if (t < 64) {
    int jr2 = t >> 4, n2 = t & 15;
    int j2 = bid * 4 + jr2;
    int b = jr2 * 64 + n2 * 4;
    float s = sAux[b] + sAux[b + 1] + sAux[b + 2] + sAux[b + 3] + b1[j2];
    ws[WS_H1 + n2 * 256 + j2] = fmaxf(s, 0.f);
  }
}

// =====================================================================
// K_ffnew: ff = h1@W2.T + b2;  slots_new = slots_mid + ff -> ws.slots, d_out
// =====================================================================
__global__ __launch_bounds__(256) void k_ffnew(
    const float* __restrict__ W2, const float* __restrict__ b2v,
    float* __restrict__ out, float* __restrict__ ws)
{
  __shared__ __align__(16) float sH[16 * 260];
  __shared__ __align__(16) float sAux[256];
  int bid = blockIdx.x, t = threadIdx.x;
  for (int n = 0; n < 16; n++)
    sH[n * 260 + t] = ws[WS_H1 + n * 256 + t];
  __syncthreads();
  int dr = t >> 6, n = (t >> 2) & 15, ks = t & 3;
  int d = bid * 4 + dr;
  const float* wrow = W2 + d * 256 + ks * 64;
  const float* srow = &sH[n * 260 + ks * 64];
  float acc = 0.f;
#pragma unroll
  for (int k = 0; k < 16; k++) {
    float4 w = *(const float4*)(wrow + k * 4);
    float4 s4 = *(const float4*)(srow + k * 4);
    acc = fmaf(w.x, s4.x, fmaf(w.y, s4.y, fmaf(w.z, s4.z, fmaf(w.w, s4.w, acc))));
  }
  sAux[t] = acc;
  __syncthreads();
  if (t < 64) {
    int dr2 = t >> 4, n2 = t & 15;
    int d2 = bid * 4 + dr2;
    int b = dr2 * 64 + n2 * 4;
    float s = sAux[b] + sAux[b + 1] + sAux[b + 2] + sAux[b + 3]
            + b2v[d2] + ws[WS_MID + n2 * 256 + d2];
    ws[WS_SLOTS + n2 * 256 + d2] = s;
    out[n2 * 256 + d2] = s;
  }
}

// =====================================================================
extern "C" void kernel_launch(void* const* d_in, const int* in_sizes, int n_in,
                              void* d_out, int out_size, void* d_ws, size_t ws_size,
                              hipStream_t stream)
{
  (void)in_sizes; (void)n_in; (void)out_size; (void)ws_size;
  const float* inputs = (const float*)d_in[0];
  const float* noise  = (const float*)d_in[1];
  const float* mu     = (const float*)d_in[2];
  const float* sigma  = (const float*)d_in[3];
  const float* Wq     = (const float*)d_in[4];
  const float* bq     = (const float*)d_in[5];
  const float* Wk     = (const float*)d_in[6];
  const float* bk     = (const float*)d_in[7];
  const float* Wv     = (const float*)d_in[8];
  const float* bv     = (const float*)d_in[9];
  const float* W_ih   = (const float*)d_in[10];
  const float* W_hh   = (const float*)d_in[11];
  const float* b_ih   = (const float*)d_in[12];
  const float* b_hh   = (const float*)d_in[13];
  const float* W1     = (const float*)d_in[14];
  const float* b1     = (const float*)d_in[15];
  const float* W2     = (const float*)d_in[16];
  const float* b2     = (const float*)d_in[17];
  const float* g_in   = (const float*)d_in[18];
  const float* be_in  = (const float*)d_in[19];
  const float* g_s    = (const float*)d_in[20];
  const float* be_s   = (const float*)d_in[21];
  const float* g_f    = (const float*)d_in[22];
  const float* be_f   = (const float*)d_in[23];
  float* ws = (float*)d_ws;
  float* out = (float*)d_out;

  hipLaunchKernelGGL(k_pre1, dim3(257), dim3(256), 0, stream,
                     Wq, bq, Wk, bk, Wv, bv, W_ih, b_ih, g_in, be_in, ws);
  hipLaunchKernelGGL(k_qkg, dim3(65), dim3(256), 0, stream,
                     noise, mu, sigma, g_s, be_s, ws, 1);
  for (int it = 0; it < 3; it++) {
    hipLaunchKernelGGL(k_big, dim3(BIG_BLOCKS), dim3(BIG_THREADS), 0, stream,
                       inputs, ws, it);
    hipLaunchKernelGGL(k_gxgh, dim3(128), dim3(256), 0, stream,
                       W_hh, b_hh, g_in, be_in, ws);
    hipLaunchKernelGGL(k_midh1, dim3(64), dim3(256), 0, stream,
                       W1, b1, g_f, be_f, ws);
    hipLaunchKernelGGL(k_ffnew, dim3(64), dim3(256), 0, stream,
                       W2, b2, out, ws);
    if (it < 2)
      hipLaunchKernelGGL(k_qkg, dim3(65), dim3(256), 0, stream,
                         noise, mu, sigma, g_s, be_s, ws, 0);
  }
}

// Round 11
// 553.057 us; speedup vs baseline: 1.2190x; 1.0001x over previous
//
#include <hip/hip_runtime.h>
#include <stdint.h>

#define B_ROWS 131072
#define SCALE 0.0625f
#define LN_EPS 1e-5f
#define ATTN_EPS 1e-8f

#define BIG_BLOCKS 512
#define BIG_THREADS 512
#define ROWS_PER_BLOCK (B_ROWS / BIG_BLOCKS)   // 256
#define ROWS_PER_WAVE  (ROWS_PER_BLOCK / 8)    // 32 (8 waves/block)
#define NSLICE 8                               // 8 atomic accumulation slices

// ---- workspace layout (float offsets) ----
#define WS_PARTU 0
#define WS_PARTS (WS_PARTU + 512*4096)           // 2097152 (only 8*16 used)
#define WS_U     (WS_PARTS + 512*16)             // 2105344 (unused)
#define WS_S     (WS_U + 4096)                   // 2109440 (unused)
#define WS_SLOTS (WS_S + 64)                     // 2109504
#define WS_MID   (WS_SLOTS + 4096)               // 2113600
#define WS_GX    (WS_MID + 4096)                 // 2117696
#define WS_GH    (WS_GX + 12288)                 // 2129984
#define WS_H1    (WS_GH + 12288)                 // 2142272
#define WS_QKG   (WS_H1 + 4096)                  // 2146368
#define WS_QB    (WS_QKG + 4096)                 // 2150464
#define WS_WIHV  (WS_QB + 64)                    // 2150528
#define WS_BGX   (WS_WIHV + 196608)              // 2347136
#define WS_WQKG  (WS_BGX + 768)                  // 2347904
#define WS_U2G   (WS_WQKG + 65536)               // 2413440
#define WS_U1    (WS_U2G + 256)                  // 2413696
#define WS_C1    (WS_U1 + 256)                   // 2413952

// =====================================================================
// K_pre1: weight compositions, 257 blocks (R3 restructure, ~10us)
// + zero the 8-slice PARTU/PARTS accumulators (re-zeroed every replay).
// =====================================================================
__global__ __launch_bounds__(256) void k_pre1(
    const float* __restrict__ Wq, const float* __restrict__ bq,
    const float* __restrict__ Wk, const float* __restrict__ bk,
    const float* __restrict__ Wv, const float* __restrict__ bv,
    const float* __restrict__ W_ih, const float* __restrict__ b_ih,
    const float* __restrict__ g_in, const float* __restrict__ be_in,
    float* __restrict__ ws)
{
  int bid = blockIdx.x, t = threadIdx.x;
  int wave = t >> 6, lane = t & 63;
  // zero atomic accumulators: blocks 0..31 cover 8*4096; block 256 PARTS
  if (bid < 32) {
#pragma unroll
    for (int q = 0; q < 4; q++)
      ws[WS_PARTU + bid * 1024 + q * 256 + t] = 0.f;
  } else if (bid == 256) {
    if (t < 128) ws[WS_PARTS + t] = 0.f;
  }
  if (bid < 192) {
    __shared__ __align__(16) float sW[4 * 256];
    __shared__ __align__(16) float sBv[256];
    int j0 = bid * 4;
#pragma unroll
    for (int r = 0; r < 4; r++) sW[r * 256 + t] = W_ih[(j0 + r) * 256 + t];
    sBv[t] = bv[t];
    __syncthreads();
    int d = t;
    float a0 = 0.f, a1 = 0.f, a2 = 0.f, a3 = 0.f;
#pragma unroll 8
    for (int dd = 0; dd < 256; dd++) {
      float v = Wv[dd * 256 + d];
      a0 = fmaf(sW[0 * 256 + dd], v, a0);
      a1 = fmaf(sW[1 * 256 + dd], v, a1);
      a2 = fmaf(sW[2 * 256 + dd], v, a2);
      a3 = fmaf(sW[3 * 256 + dd], v, a3);
    }
    ws[WS_WIHV + (j0 + 0) * 256 + d] = a0;
    ws[WS_WIHV + (j0 + 1) * 256 + d] = a1;
    ws[WS_WIHV + (j0 + 2) * 256 + d] = a2;
    ws[WS_WIHV + (j0 + 3) * 256 + d] = a3;
    float s = 0.f;
#pragma unroll
    for (int q = 0; q < 4; q++) {
      int idx = lane * 4 + q;
      s = fmaf(sW[wave * 256 + idx], sBv[idx], s);
    }
#pragma unroll
    for (int m = 1; m <= 32; m <<= 1) s += __shfl_xor(s, m);
    if (lane == 0) ws[WS_BGX + j0 + wave] = b_ih[j0 + wave] + s;
  } else if (bid < 256) {
    __shared__ __align__(16) float sKc[4 * 256];
    __shared__ __align__(16) float sBq[256];
    int c0 = (bid - 192) * 4;
#pragma unroll
    for (int r = 0; r < 4; r++) sKc[r * 256 + t] = Wk[t * 256 + c0 + r];
    sBq[t] = bq[t];
    __syncthreads();
    int d = t;
    float a0 = 0.f, a1 = 0.f, a2 = 0.f, a3 = 0.f;
#pragma unroll 8
    for (int i = 0; i < 256; i++) {
      float wq = Wq[i * 256 + d];
      a0 = fmaf(wq, sKc[0 * 256 + i], a0);
      a1 = fmaf(wq, sKc[1 * 256 + i], a1);
      a2 = fmaf(wq, sKc[2 * 256 + i], a2);
      a3 = fmaf(wq, sKc[3 * 256 + i], a3);
    }
    ws[WS_WQKG + (c0 + 0) * 256 + d] = SCALE * g_in[c0 + 0] * a0;
    ws[WS_WQKG + (c0 + 1) * 256 + d] = SCALE * g_in[c0 + 1] * a1;
    ws[WS_WQKG + (c0 + 2) * 256 + d] = SCALE * g_in[c0 + 2] * a2;
    ws[WS_WQKG + (c0 + 3) * 256 + d] = SCALE * g_in[c0 + 3] * a3;
    float s = 0.f;
#pragma unroll
    for (int q = 0; q < 4; q++) {
      int idx = lane * 4 + q;
      s = fmaf(sBq[idx], sKc[wave * 256 + idx], s);
    }
#pragma unroll
    for (int m = 1; m <= 32; m <<= 1) s += __shfl_xor(s, m);
    if (lane == 0) ws[WS_U2G + c0 + wave] = SCALE * g_in[c0 + wave] * s;
  } else {
    __shared__ __align__(16) float sBe[256];
    __shared__ __align__(16) float sT2[256];
    sBe[t] = be_in[t];
    __syncthreads();
    float a = 0.f;
#pragma unroll 8
    for (int dp = 0; dp < 256; dp += 4) {
      float4 w = *(const float4*)(Wk + t * 256 + dp);
      a = fmaf(w.x, sBe[dp], fmaf(w.y, sBe[dp + 1],
          fmaf(w.z, sBe[dp + 2], fmaf(w.w, sBe[dp + 3], a))));
    }
    sT2[t] = a + bk[t];
    __syncthreads();
    float u = 0.f;
#pragma unroll 8
    for (int i = 0; i < 256; i++)
      u = fmaf(Wq[i * 256 + t], sT2[i], u);
    ws[WS_U1 + t] = u;
    if (wave == 0) {
      float s = 0.f;
#pragma unroll
      for (int q = 0; q < 4; q++) {
        int idx = lane * 4 + q;
        s = fmaf(bq[idx], sT2[idx], s);
      }
#pragma unroll
      for (int m = 1; m <= 32; m <<= 1) s += __shfl_xor(s, m);
      if (lane == 0) ws[WS_C1] = s;
    }
  }
}

// =====================================================================
// K_qkg: s = LN(slots); qkg/qb. init: slots = mu + sigma*noise.
// =====================================================================
__global__ __launch_bounds__(256) void k_qkg(
    const float* __restrict__ noise, const float* __restrict__ mu,
    const float* __restrict__ sigma, const float* __restrict__ g_s,
    const float* __restrict__ be_s, float* __restrict__ ws, int init)
{
  __shared__ __align__(16) float sS[16 * 260];
  __shared__ __align__(16) float sAux[512];
  __shared__ __align__(16) float sStat[32];
  int bid = blockIdx.x, t = threadIdx.x;
  for (int n = 0; n < 16; n++) {
    float v;
    if (init) v = fmaf(sigma[t], noise[n * 256 + t], mu[t]);
    else      v = ws[WS_SLOTS + n * 256 + t];
    sS[n * 260 + t] = v;
    if (init && bid == 0) ws[WS_SLOTS + n * 256 + t] = v;
  }
  __syncthreads();
  { int n = t >> 4, c = t & 15;
    float s1 = 0.f, s2 = 0.f;
    for (int k = 0; k < 16; k++) {
      float x = sS[n * 260 + c * 16 + k];
      s1 += x; s2 = fmaf(x, x, s2);
    }
    sAux[n * 16 + c] = s1; sAux[256 + n * 16 + c] = s2; }
  __syncthreads();
  if (t < 16) {
    float s1 = 0.f, s2 = 0.f;
    for (int c = 0; c < 16; c++) { s1 += sAux[t * 16 + c]; s2 += sAux[256 + t * 16 + c]; }
    float m = s1 * (1.f / 256.f);
    float v = fmaxf(fmaf(-m, m, s2 * (1.f / 256.f)), 0.f);
    sStat[t] = m; sStat[16 + t] = rsqrtf(v + LN_EPS);
  }
  __syncthreads();
  { float gs = g_s[t], bs = be_s[t];
    for (int n = 0; n < 16; n++) {
      float m = sStat[n], rs = sStat[16 + n];
      sS[n * 260 + t] = fmaf((sS[n * 260 + t] - m) * rs, gs, bs);
    } }
  __syncthreads();
  if (bid < 64) {
    int cr = t >> 6, n = (t >> 2) & 15, ks = t & 3;
    int c = bid * 4 + cr;
    const float* wrow = ws + WS_WQKG + c * 256 + ks * 64;
    const float* srow = &sS[n * 260 + ks * 64];
    float acc = 0.f;
#pragma unroll
    for (int i = 0; i < 16; i++) {
      float4 w = *(const float4*)(wrow + i * 4);
      float4 s4 = *(const float4*)(srow + i * 4);
      acc = fmaf(w.x, s4.x, fmaf(w.y, s4.y, fmaf(w.z, s4.z, fmaf(w.w, s4.w, acc))));
    }
    sAux[t] = acc;
    __syncthreads();
    if (t < 64) {
      int cr2 = t >> 4, n2 = t & 15;
      int c2 = bid * 4 + cr2;
      int b = cr2 * 64 + n2 * 4;
      float s = sAux[b] + sAux[b + 1] + sAux[b + 2] + sAux[b + 3];
      ws[WS_QKG + n2 * 256 + c2] = s + ws[WS_U2G + c2];
    }
  } else {
    int n = t >> 4, ks = t & 15;
    float acc = 0.f;
    for (int k = 0; k < 16; k++)
      acc = fmaf(sS[n * 260 + ks * 16 + k], ws[WS_U1 + ks * 16 + k], acc);
    sAux[t] = acc;
    __syncthreads();
    if (t < 16) {
      float s = 0.f;
      for (int k = 0; k < 16; k++) s += sAux[t * 16 + k];
      ws[WS_QB + t] = SCALE * (s + ws[WS_C1]);
    }
  }
}

// =====================================================================
// K_big: R9-measured form (98.5us, bit-exact): pair-ILP + distance-1
// prefetch + merged 12-var butterfly, UNCONDITIONAL stats. R10's
// iter-cached LN stats REVERTED (cost +17us/dispatch: per-pair L2 loads
// stalled the loop; VGPR 108->128). Only change vs R9: epilogue writes
// 8 atomic slices (slice = bid & 7) for the k_red-free slot chain.
// =====================================================================
__global__ __launch_bounds__(512, 2) void k_big(
    const float* __restrict__ X, float* __restrict__ ws)
{
  __shared__ __align__(16) float red[4 * 4096];   // 64 KB
  __shared__ __align__(16) float redS[128];       // 8 waves x 16
  int t = threadIdx.x;
  int wave = t >> 6, lane = t & 63;
  int p = lane >> 4, g = lane & 15;

  const float* qkg = ws + WS_QKG;
  float qw[4][16];
  float qs[4];
#pragma unroll
  for (int i = 0; i < 4; i++) {
    const float* rp = qkg + (4 * p + i) * 256 + g * 16;
#pragma unroll
    for (int jq = 0; jq < 4; jq++) {
      float4 v4 = *(const float4*)(rp + 4 * jq);
      qw[i][4 * jq + 0] = v4.x; qw[i][4 * jq + 1] = v4.y;
      qw[i][4 * jq + 2] = v4.z; qw[i][4 * jq + 3] = v4.w;
    }
    float s = 0.f;
#pragma unroll
    for (int j = 0; j < 16; j++) s += qw[i][j];
    qs[i] = s;
  }
#pragma unroll
  for (int m = 1; m <= 8; m <<= 1) {
#pragma unroll
    for (int i = 0; i < 4; i++) qs[i] += __shfl_xor(qs[i], m);
  }
  float qb0[4];
  {
    float4 q4 = *(const float4*)(ws + WS_QB + 4 * p);
    qb0[0] = q4.x; qb0[1] = q4.y; qb0[2] = q4.z; qb0[3] = q4.w;
  }

  float P[4][16];
#pragma unroll
  for (int i = 0; i < 4; i++)
#pragma unroll
    for (int j = 0; j < 16; j++) P[i][j] = 0.f;
  float Q[4] = {0.f, 0.f, 0.f, 0.f};
  float Sa[4] = {0.f, 0.f, 0.f, 0.f};

  size_t rowbase = (size_t)blockIdx.x * ROWS_PER_BLOCK + (size_t)wave * ROWS_PER_WAVE;
  const float* base = X + rowbase * 256 + g * 16;

  float4 cA0 = *(const float4*)(base + 0);
  float4 cB0 = *(const float4*)(base + 4);
  float4 cC0 = *(const float4*)(base + 8);
  float4 cD0 = *(const float4*)(base + 12);
  float4 cA1 = *(const float4*)(base + 256);
  float4 cB1 = *(const float4*)(base + 260);
  float4 cC1 = *(const float4*)(base + 264);
  float4 cD1 = *(const float4*)(base + 268);

#pragma unroll 1
  for (int r = 0; r < ROWS_PER_WAVE; r += 2) {
    const float* nx = base + (size_t)((r + 2 < ROWS_PER_WAVE) ? (r + 2) : 0) * 256;
    float4 pA0 = *(const float4*)(nx + 0);
    float4 pB0 = *(const float4*)(nx + 4);
    float4 pC0 = *(const float4*)(nx + 8);
    float4 pD0 = *(const float4*)(nx + 12);
    float4 pA1 = *(const float4*)(nx + 256);
    float4 pB1 = *(const float4*)(nx + 260);
    float4 pC1 = *(const float4*)(nx + 264);
    float4 pD1 = *(const float4*)(nx + 268);

    float x0[16], x1[16];
    x0[0] = cA0.x; x0[1] = cA0.y; x0[2] = cA0.z; x0[3] = cA0.w;
    x0[4] = cB0.x; x0[5] = cB0.y; x0[6] = cB0.z; x0[7] = cB0.w;
    x0[8] = cC0.x; x0[9] = cC0.y; x0[10] = cC0.z; x0[11] = cC0.w;
    x0[12] = cD0.x; x0[13] = cD0.y; x0[14] = cD0.z; x0[15] = cD0.w;
    x1[0] = cA1.x; x1[1] = cA1.y; x1[2] = cA1.z; x1[3] = cA1.w;
    x1[4] = cB1.x; x1[5] = cB1.y; x1[6] = cB1.z; x1[7] = cB1.w;
    x1[8] = cC1.x; x1[9] = cC1.y; x1[10] = cC1.z; x1[11] = cC1.w;
    x1[12] = cD1.x; x1[13] = cD1.y; x1[14] = cD1.z; x1[15] = cD1.w;

    // ---- partial sums: stats AND dots together (12 parallel chains) ----
    float s10 = 0.f, s20 = 0.f, s11 = 0.f, s21 = 0.f;
    float d0[4] = {0.f, 0.f, 0.f, 0.f};
    float d1[4] = {0.f, 0.f, 0.f, 0.f};
#pragma unroll
    for (int j = 0; j < 16; j++) {
      s10 += x0[j]; s20 = fmaf(x0[j], x0[j], s20);
      s11 += x1[j]; s21 = fmaf(x1[j], x1[j], s21);
#pragma unroll
      for (int i = 0; i < 4; i++) {
        d0[i] = fmaf(qw[i][j], x0[j], d0[i]);
        d1[i] = fmaf(qw[i][j], x1[j], d1[i]);
      }
    }
    // ---- ONE merged 12-var butterfly (4 levels over 16 lanes) ----
#pragma unroll
    for (int m = 1; m <= 8; m <<= 1) {
      s10 += __shfl_xor(s10, m); s11 += __shfl_xor(s11, m);
      s20 += __shfl_xor(s20, m); s21 += __shfl_xor(s21, m);
#pragma unroll
      for (int i = 0; i < 4; i++) {
        d0[i] += __shfl_xor(d0[i], m);
        d1[i] += __shfl_xor(d1[i], m);
      }
    }
    float mean0 = s10 * (1.f / 256.f), mean1 = s11 * (1.f / 256.f);
    float var0 = fmaxf(fmaf(-mean0, mean0, s20 * (1.f / 256.f)), 0.f);
    float var1 = fmaxf(fmaf(-mean1, mean1, s21 * (1.f / 256.f)), 0.f);
    float rs0 = rsqrtf(var0 + LN_EPS), rs1 = rsqrtf(var1 + LN_EPS);
    float mrs0 = mean0 * rs0, mrs1 = mean1 * rs1;

    float dsc0[4], dsc1[4];
#pragma unroll
    for (int i = 0; i < 4; i++) {
      dsc0[i] = fmaf(rs0, d0[i], fmaf(-mrs0, qs[i], qb0[i]));
      dsc1[i] = fmaf(rs1, d1[i], fmaf(-mrs1, qs[i], qb0[i]));
    }

    // ---- softmax, both rows interleaved ----
    float mx0 = fmaxf(fmaxf(dsc0[0], dsc0[1]), fmaxf(dsc0[2], dsc0[3]));
    float mx1 = fmaxf(fmaxf(dsc1[0], dsc1[1]), fmaxf(dsc1[2], dsc1[3]));
    mx0 = fmaxf(mx0, __shfl_xor(mx0, 16)); mx1 = fmaxf(mx1, __shfl_xor(mx1, 16));
    mx0 = fmaxf(mx0, __shfl_xor(mx0, 32)); mx1 = fmaxf(mx1, __shfl_xor(mx1, 32));
    float e0[4], e1[4];
#pragma unroll
    for (int i = 0; i < 4; i++) {
      e0[i] = __expf(dsc0[i] - mx0);
      e1[i] = __expf(dsc1[i] - mx1);
    }
    float se0 = e0[0] + e0[1] + e0[2] + e0[3];
    float se1 = e1[0] + e1[1] + e1[2] + e1[3];
    se0 += __shfl_xor(se0, 16); se1 += __shfl_xor(se1, 16);
    se0 += __shfl_xor(se0, 32); se1 += __shfl_xor(se1, 32);
    float inv0 = 1.0f / se0, inv1 = 1.0f / se1;
    float a0v[4], ar0[4], a1v[4], ar1[4];
#pragma unroll
    for (int i = 0; i < 4; i++) {
      a0v[i] = fmaf(e0[i], inv0, ATTN_EPS); ar0[i] = a0v[i] * rs0;
      a1v[i] = fmaf(e1[i], inv1, ATTN_EPS); ar1[i] = a1v[i] * rs1;
    }

    // ---- P accumulation (shared accumulators, row r then r+1) ----
#pragma unroll
    for (int j = 0; j < 16; j++) {
#pragma unroll
      for (int i = 0; i < 4; i++) {
        P[i][j] = fmaf(ar0[i], x0[j], P[i][j]);
        P[i][j] = fmaf(ar1[i], x1[j], P[i][j]);
      }
    }
#pragma unroll
    for (int i = 0; i < 4; i++) {
      Q[i] = fmaf(a0v[i], mrs0, Q[i]);
      Q[i] = fmaf(a1v[i], mrs1, Q[i]);
      Sa[i] += a0v[i];
      Sa[i] += a1v[i];
    }

    cA0 = pA0; cB0 = pB0; cC0 = pC0; cD0 = pD0;
    cA1 = pA1; cB1 = pB1; cC1 = pC1; cD1 = pD1;
  }

  // Two-stage cross-wave reduce in 64KB LDS (Uy = P - Q per slot/elem).
  int slot = wave & 3;
  if (wave < 4) {
#pragma unroll
    for (int i = 0; i < 4; i++) {
#pragma unroll
      for (int jq = 0; jq < 4; jq++) {
        float4 v4;
        v4.x = P[i][4 * jq + 0] - Q[i]; v4.y = P[i][4 * jq + 1] - Q[i];
        v4.z = P[i][4 * jq + 2] - Q[i]; v4.w = P[i][4 * jq + 3] - Q[i];
        *(float4*)&red[slot * 4096 + (4 * p + i) * 256 + g * 16 + jq * 4] = v4;
      }
    }
  }
  if (g == 0) {
#pragma unroll
    for (int i = 0; i < 4; i++) redS[wave * 16 + 4 * p + i] = Sa[i];
  }
  __syncthreads();
  if (wave >= 4) {
#pragma unroll
    for (int i = 0; i < 4; i++) {
#pragma unroll
      for (int jq = 0; jq < 4; jq++) {
        float4* dst = (float4*)&red[slot * 4096 + (4 * p + i) * 256 + g * 16 + jq * 4];
        float4 c = *dst;
        c.x += P[i][4 * jq + 0] - Q[i]; c.y += P[i][4 * jq + 1] - Q[i];
        c.z += P[i][4 * jq + 2] - Q[i]; c.w += P[i][4 * jq + 3] - Q[i];
        *dst = c;
      }
    }
  }
  __syncthreads();
  int slice = blockIdx.x & 7;
#pragma unroll
  for (int k = 0; k < 8; k++) {
    int idx = k * 512 + t;
    float v = red[idx] + red[4096 + idx] + red[8192 + idx] + red[12288 + idx];
    atomicAdd(&ws[WS_PARTU + (size_t)slice * 4096 + idx], v);
  }
  if (t < 16) {
    float sv = 0.f;
#pragma unroll
    for (int w = 0; w < 8; w++) sv += redS[w * 16 + t];
    atomicAdd(&ws[WS_PARTS + slice * 16 + t], sv);
  }
}

// =====================================================================
// K_gxgh: k_red-free — gx blocks inline-reduce the 8 L2-resident
// PARTU slices (128KB) and PARTS directly.
// bid<64:  gx[n][j] = W_ihv[j]·(g_in*(U[n]/S[n]) + be_in) + bgx[j]
// bid>=64: gh[n][j] = W_hh[j]·slots_prev[n] + b_hh[j]
// =====================================================================
__global__ __launch_bounds__(256) void k_gxgh(
    const float* __restrict__ W_hh, const float* __restrict__ b_hh,
    const float* __restrict__ g_in, const float* __restrict__ be_in,
    float* __restrict__ ws)
{
  __shared__ __align__(16) float sU[16 * 260];
  __shared__ __align__(16) float sInv[16];
  int bid = blockIdx.x, t = threadIdx.x;
  bool isgx = bid < 64;
  if (isgx && t < 16) {
    float s = 0.f;
#pragma unroll
    for (int sl = 0; sl < NSLICE; sl++) s += ws[WS_PARTS + sl * 16 + t];
    sInv[t] = 1.0f / s;
  }
  __syncthreads();
  if (isgx) {
    float gi = g_in[t], bi = be_in[t];
    for (int n = 0; n < 16; n++) {
      float acc = 0.f;
#pragma unroll
      for (int sl = 0; sl < NSLICE; sl++)
        acc += ws[WS_PARTU + (size_t)sl * 4096 + n * 256 + t];
      sU[n * 260 + t] = fmaf(gi * acc, sInv[n], bi);
    }
  } else {
    for (int n = 0; n < 16; n++)
      sU[n * 260 + t] = ws[WS_SLOTS + n * 256 + t];
  }
  __syncthreads();
  int jr = t >> 4, n = t & 15;
  if (jr < 12) {
    int j = (isgx ? bid : bid - 64) * 12 + jr;
    const float* srow = &sU[n * 260];
    const float* wrow = isgx ? (ws + WS_WIHV + j * 256) : (W_hh + j * 256);
    float acc = isgx ? ws[WS_BGX + j] : b_hh[j];
#pragma unroll 8
    for (int k = 0; k < 64; k++) {
      float4 w = *(const float4*)(wrow + k * 4);
      float4 s4 = *(const float4*)(srow + k * 4);
      acc = fmaf(w.x, s4.x, fmaf(w.y, s4.y, fmaf(w.z, s4.z, fmaf(w.w, s4.w, acc))));
    }
    if (isgx) ws[WS_GX + n * 768 + j] = acc;
    else      ws[WS_GH + n * 768 + j] = acc;
  }
}

// =====================================================================
// K_midh1: GRU gates -> slots_mid; LN(g_f,be_f); h1 = relu(lnf@W1.T + b1)
// + zeroes the 8 PARTU/PARTS slices for the next iteration's k_big.
// =====================================================================
__global__ __launch_bounds__(256) void k_midh1(
    const float* __restrict__ W1, const float* __restrict__ b1,
    const float* __restrict__ g_f, const float* __restrict__ be_f,
    float* __restrict__ ws)
{
  __shared__ __align__(16) float sM[16 * 260];
  __shared__ __align__(16) float sAux[512];
  __shared__ __align__(16) float sStat[32];
  int bid = blockIdx.x, t = threadIdx.x;
  {
    int gid = bid * 256 + t;               // 0..16383
    ws[WS_PARTU + gid] = 0.f;
    ws[WS_PARTU + 16384 + gid] = 0.f;      // 32768 = 8 slices x 4096
    if (gid < 128) ws[WS_PARTS + gid] = 0.f;
  }
  for (int n = 0; n < 16; n++) {
    float xr = ws[WS_GX + n * 768 + t],       hr = ws[WS_GH + n * 768 + t];
    float xz = ws[WS_GX + n * 768 + 256 + t], hz = ws[WS_GH + n * 768 + 256 + t];
    float xn = ws[WS_GX + n * 768 + 512 + t], hn = ws[WS_GH + n * 768 + 512 + t];
    float sp = ws[WS_SLOTS + n * 256 + t];
    float r = 1.f / (1.f + __expf(-(xr + hr)));
    float z = 1.f / (1.f + __expf(-(xz + hz)));
    float nn = tanhf(fmaf(r, hn, xn));
    float mid = fmaf(z, sp - nn, nn);
    sM[n * 260 + t] = mid;
    if (bid == 0) ws[WS_MID + n * 256 + t] = mid;
  }
  __syncthreads();
  { int n = t >> 4, c = t & 15;
    float s1 = 0.f, s2 = 0.f;
    for (int k = 0; k < 16; k++) {
      float x = sM[n * 260 + c * 16 + k];
      s1 += x; s2 = fmaf(x, x, s2);
    }
    sAux[n * 16 + c] = s1; sAux[256 + n * 16 + c] = s2; }
  __syncthreads();
  if (t < 16) {
    float s1 = 0.f, s2 = 0.f;
    for (int c = 0; c < 16; c++) { s1 += sAux[t * 16 + c]; s2 += sAux[256 + t * 16 + c]; }
    float m = s1 * (1.f / 256.f);
    float v = fmaxf(fmaf(-m, m, s2 * (1.f / 256.f)), 0.f);
    sStat[t] = m; sStat[16 + t] = rsqrtf(v + LN_EPS);
  }
  __syncthreads();
  { float gf = g_f[t], bf = be_f[t];
    for (int n = 0; n < 16; n++) {
      float m = sStat[n], rs = sStat[16 + n];
      sM[n * 260 + t] = fmaf((sM[n * 260 + t] - m) * rs, gf, bf);
    } }
  __syncthreads();
  int jr = t >> 6, n = (t >> 2) & 15, ks = t & 3;
  int j = bid * 4 + jr;
  const float* wrow = W1 + j * 256 + ks * 64;
  const float* srow = &sM[n * 260 + ks * 64];
  float acc = 0.f;
#pragma unroll
  for (int k = 0; k < 16; k++) {
    float4 w = *(const float4*)(wrow + k * 4);
    float4 s4 = *(const float4*)(srow + k * 4);
    acc = fmaf(w.x, s4.x, fmaf(w.y, s4.y, fmaf(w.z, s4.z, fmaf(w.w, s4.w, acc))));
  }
  sAux[t] = acc;
  __syncthreads();
  if (t < 64) {
    int jr2 = t >> 4, n2 = t & 15;
    int j2 = bid * 4 + jr2;
    int b = jr2 * 64 + n2 * 4;
    float s = sAux[b] + sAux[b + 1] + sAux[b + 2] + sAux[b + 3] + b1[j2];
    ws[WS_H1 + n2 * 256 + j2] = fmaxf(s, 0.f);
  }
}

// =====================================================================
// K_ffnew: ff = h1@W2.T + b2;  slots_new = slots_mid + ff -> ws.slots, d_out
// =====================================================================
__global__ __launch_bounds__(256) void k_ffnew(
    const float* __restrict__ W2, const float* __restrict__ b2v,
    float* __restrict__ out, float* __restrict__ ws)
{
  __shared__ __align__(16) float sH[16 * 260];
  __shared__ __align__(16) float sAux[256];
  int bid = blockIdx.x, t = threadIdx.x;
  for (int n = 0; n < 16; n++)
    sH[n * 260 + t] = ws[WS_H1 + n * 256 + t];
  __syncthreads();
  int dr = t >> 6, n = (t >> 2) & 15, ks = t & 3;
  int d = bid * 4 + dr;
  const float* wrow = W2 + d * 256 + ks * 64;
  const float* srow = &sH[n * 260 + ks * 64];
  float acc = 0.f;
#pragma unroll
  for (int k = 0; k < 16; k++) {
    float4 w = *(const float4*)(wrow + k * 4);
    float4 s4 = *(const float4*)(srow + k * 4);
    acc = fmaf(w.x, s4.x, fmaf(w.y, s4.y, fmaf(w.z, s4.z, fmaf(w.w, s4.w, acc))));
  }
  sAux[t] = acc;
  __syncthreads();
  if (t < 64) {
    int dr2 = t >> 4, n2 = t & 15;
    int d2 = bid * 4 + dr2;
    int b = dr2 * 64 + n2 * 4;
    float s = sAux[b] + sAux[b + 1] + sAux[b + 2] + sAux[b + 3]
            + b2v[d2] + ws[WS_MID + n2 * 256 + d2];
    ws[WS_SLOTS + n2 * 256 + d2] = s;
    out[n2 * 256 + d2] = s;
  }
}

// =====================================================================
extern "C" void kernel_launch(void* const* d_in, const int* in_sizes, int n_in,
                              void* d_out, int out_size, void* d_ws, size_t ws_size,
                              hipStream_t stream)
{
  (void)in_sizes; (void)n_in; (void)out_size; (void)ws_size;
  const float* inputs = (const float*)d_in[0];
  const float* noise  = (const float*)d_in[1];
  const float* mu     = (const float*)d_in[2];
  const float* sigma  = (const float*)d_in[3];
  const float* Wq     = (const float*)d_in[4];
  const float* bq     = (const float*)d_in[5];
  const float* Wk     = (const float*)d_in[6];
  const float* bk     = (const float*)d_in[7];
  const float* Wv     = (const float*)d_in[8];
  const float* bv     = (const float*)d_in[9];
  const float* W_ih   = (const float*)d_in[10];
  const float* W_hh   = (const float*)d_in[11];
  const float* b_ih   = (const float*)d_in[12];
  const float* b_hh   = (const float*)d_in[13];
  const float* W1     = (const float*)d_in[14];
  const float* b1     = (const float*)d_in[15];
  const float* W2     = (const float*)d_in[16];
  const float* b2     = (const float*)d_in[17];
  const float* g_in   = (const float*)d_in[18];
  const float* be_in  = (const float*)d_in[19];
  const float* g_s    = (const float*)d_in[20];
  const float* be_s   = (const float*)d_in[21];
  const float* g_f    = (const float*)d_in[22];
  const float* be_f   = (const float*)d_in[23];
  float* ws = (float*)d_ws;
  float* out = (float*)d_out;

  hipLaunchKernelGGL(k_pre1, dim3(257), dim3(256), 0, stream,
                     Wq, bq, Wk, bk, Wv, bv, W_ih, b_ih, g_in, be_in, ws);
  hipLaunchKernelGGL(k_qkg, dim3(65), dim3(256), 0, stream,
                     noise, mu, sigma, g_s, be_s, ws, 1);
  for (int it = 0; it < 3; it++) {
    hipLaunchKernelGGL(k_big, dim3(BIG_BLOCKS), dim3(BIG_THREADS), 0, stream,
                       inputs, ws);
    hipLaunchKernelGGL(k_gxgh, dim3(128), dim3(256), 0, stream,
                       W_hh, b_hh, g_in, be_in, ws);
    hipLaunchKernelGGL(k_midh1, dim3(64), dim3(256), 0, stream,
                       W1, b1, g_f, be_f, ws);
    hipLaunchKernelGGL(k_ffnew, dim3(64), dim3(256), 0, stream,
                       W2, b2, out, ws);
    if (it < 2)
      hipLaunchKernelGGL(k_qkg, dim3(65), dim3(256), 0, stream,
                         noise, mu, sigma, g_s, be_s, ws, 0);
  }
}

// Round 12
// 549.002 us; speedup vs baseline: 1.2280x; 1.0074x over previous
//
#include <hip/hip_runtime.h>
#include <stdint.h>

#define B_ROWS 131072
#define SCALE 0.0625f
#define LN_EPS 1e-5f
#define ATTN_EPS 1e-8f

#define BIG_BLOCKS 512
#define BIG_THREADS 512
#define ROWS_PER_BLOCK (B_ROWS / BIG_BLOCKS)   // 256
#define ROWS_PER_WAVE  (ROWS_PER_BLOCK / 8)    // 32 (8 waves/block)
#define NSLICE 8                               // 8 atomic accumulation slices

// ---- workspace layout (float offsets) ----
#define WS_PARTU 0
#define WS_PARTS (WS_PARTU + 512*4096)           // 2097152 (only 8*16 used)
#define WS_U     (WS_PARTS + 512*16)             // 2105344 (unused)
#define WS_S     (WS_U + 4096)                   // 2109440 (unused)
#define WS_SLOTS (WS_S + 64)                     // 2109504
#define WS_MID   (WS_SLOTS + 4096)               // 2113600 (unused now)
#define WS_GX    (WS_MID + 4096)                 // 2117696
#define WS_GH    (WS_GX + 12288)                 // 2129984
#define WS_H1    (WS_GH + 12288)                 // 2142272 (unused now)
#define WS_QKG   (WS_H1 + 4096)                  // 2146368
#define WS_QB    (WS_QKG + 4096)                 // 2150464
#define WS_WIHV  (WS_QB + 64)                    // 2150528
#define WS_BGX   (WS_WIHV + 196608)              // 2347136
#define WS_WQKG  (WS_BGX + 768)                  // 2347904
#define WS_U2G   (WS_WQKG + 65536)               // 2413440
#define WS_U1    (WS_U2G + 256)                  // 2413696
#define WS_C1    (WS_U1 + 256)                   // 2413952

// 16-element dot, both pointers 16B-aligned (R6-proven pattern)
__device__ __forceinline__ float dot16(const float* __restrict__ w, const float* s)
{
  float4 w0 = *(const float4*)(w);
  float4 w1 = *(const float4*)(w + 4);
  float4 w2 = *(const float4*)(w + 8);
  float4 w3 = *(const float4*)(w + 12);
  float4 s0 = *(const float4*)(s);
  float4 s1 = *(const float4*)(s + 4);
  float4 s2 = *(const float4*)(s + 8);
  float4 s3 = *(const float4*)(s + 12);
  float a = 0.f;
  a = fmaf(w0.x, s0.x, a); a = fmaf(w0.y, s0.y, a);
  a = fmaf(w0.z, s0.z, a); a = fmaf(w0.w, s0.w, a);
  a = fmaf(w1.x, s1.x, a); a = fmaf(w1.y, s1.y, a);
  a = fmaf(w1.z, s1.z, a); a = fmaf(w1.w, s1.w, a);
  a = fmaf(w2.x, s2.x, a); a = fmaf(w2.y, s2.y, a);
  a = fmaf(w2.z, s2.z, a); a = fmaf(w2.w, s2.w, a);
  a = fmaf(w3.x, s3.x, a); a = fmaf(w3.y, s3.y, a);
  a = fmaf(w3.z, s3.z, a); a = fmaf(w3.w, s3.w, a);
  return a;
}

// =====================================================================
// K_pre1: weight compositions, 257 blocks (R3 restructure, ~10us)
// + zero the 8-slice PARTU/PARTS accumulators (re-zeroed every replay).
// =====================================================================
__global__ __launch_bounds__(256) void k_pre1(
    const float* __restrict__ Wq, const float* __restrict__ bq,
    const float* __restrict__ Wk, const float* __restrict__ bk,
    const float* __restrict__ Wv, const float* __restrict__ bv,
    const float* __restrict__ W_ih, const float* __restrict__ b_ih,
    const float* __restrict__ g_in, const float* __restrict__ be_in,
    float* __restrict__ ws)
{
  int bid = blockIdx.x, t = threadIdx.x;
  int wave = t >> 6, lane = t & 63;
  // zero atomic accumulators: blocks 0..31 cover 8*4096; block 256 PARTS
  if (bid < 32) {
#pragma unroll
    for (int q = 0; q < 4; q++)
      ws[WS_PARTU + bid * 1024 + q * 256 + t] = 0.f;
  } else if (bid == 256) {
    if (t < 128) ws[WS_PARTS + t] = 0.f;
  }
  if (bid < 192) {
    __shared__ __align__(16) float sW[4 * 256];
    __shared__ __align__(16) float sBv[256];
    int j0 = bid * 4;
#pragma unroll
    for (int r = 0; r < 4; r++) sW[r * 256 + t] = W_ih[(j0 + r) * 256 + t];
    sBv[t] = bv[t];
    __syncthreads();
    int d = t;
    float a0 = 0.f, a1 = 0.f, a2 = 0.f, a3 = 0.f;
#pragma unroll 8
    for (int dd = 0; dd < 256; dd++) {
      float v = Wv[dd * 256 + d];
      a0 = fmaf(sW[0 * 256 + dd], v, a0);
      a1 = fmaf(sW[1 * 256 + dd], v, a1);
      a2 = fmaf(sW[2 * 256 + dd], v, a2);
      a3 = fmaf(sW[3 * 256 + dd], v, a3);
    }
    ws[WS_WIHV + (j0 + 0) * 256 + d] = a0;
    ws[WS_WIHV + (j0 + 1) * 256 + d] = a1;
    ws[WS_WIHV + (j0 + 2) * 256 + d] = a2;
    ws[WS_WIHV + (j0 + 3) * 256 + d] = a3;
    float s = 0.f;
#pragma unroll
    for (int q = 0; q < 4; q++) {
      int idx = lane * 4 + q;
      s = fmaf(sW[wave * 256 + idx], sBv[idx], s);
    }
#pragma unroll
    for (int m = 1; m <= 32; m <<= 1) s += __shfl_xor(s, m);
    if (lane == 0) ws[WS_BGX + j0 + wave] = b_ih[j0 + wave] + s;
  } else if (bid < 256) {
    __shared__ __align__(16) float sKc[4 * 256];
    __shared__ __align__(16) float sBq[256];
    int c0 = (bid - 192) * 4;
#pragma unroll
    for (int r = 0; r < 4; r++) sKc[r * 256 + t] = Wk[t * 256 + c0 + r];
    sBq[t] = bq[t];
    __syncthreads();
    int d = t;
    float a0 = 0.f, a1 = 0.f, a2 = 0.f, a3 = 0.f;
#pragma unroll 8
    for (int i = 0; i < 256; i++) {
      float wq = Wq[i * 256 + d];
      a0 = fmaf(wq, sKc[0 * 256 + i], a0);
      a1 = fmaf(wq, sKc[1 * 256 + i], a1);
      a2 = fmaf(wq, sKc[2 * 256 + i], a2);
      a3 = fmaf(wq, sKc[3 * 256 + i], a3);
    }
    ws[WS_WQKG + (c0 + 0) * 256 + d] = SCALE * g_in[c0 + 0] * a0;
    ws[WS_WQKG + (c0 + 1) * 256 + d] = SCALE * g_in[c0 + 1] * a1;
    ws[WS_WQKG + (c0 + 2) * 256 + d] = SCALE * g_in[c0 + 2] * a2;
    ws[WS_WQKG + (c0 + 3) * 256 + d] = SCALE * g_in[c0 + 3] * a3;
    float s = 0.f;
#pragma unroll
    for (int q = 0; q < 4; q++) {
      int idx = lane * 4 + q;
      s = fmaf(sBq[idx], sKc[wave * 256 + idx], s);
    }
#pragma unroll
    for (int m = 1; m <= 32; m <<= 1) s += __shfl_xor(s, m);
    if (lane == 0) ws[WS_U2G + c0 + wave] = SCALE * g_in[c0 + wave] * s;
  } else {
    __shared__ __align__(16) float sBe[256];
    __shared__ __align__(16) float sT2[256];
    sBe[t] = be_in[t];
    __syncthreads();
    float a = 0.f;
#pragma unroll 8
    for (int dp = 0; dp < 256; dp += 4) {
      float4 w = *(const float4*)(Wk + t * 256 + dp);
      a = fmaf(w.x, sBe[dp], fmaf(w.y, sBe[dp + 1],
          fmaf(w.z, sBe[dp + 2], fmaf(w.w, sBe[dp + 3], a))));
    }
    sT2[t] = a + bk[t];
    __syncthreads();
    float u = 0.f;
#pragma unroll 8
    for (int i = 0; i < 256; i++)
      u = fmaf(Wq[i * 256 + t], sT2[i], u);
    ws[WS_U1 + t] = u;
    if (wave == 0) {
      float s = 0.f;
#pragma unroll
      for (int q = 0; q < 4; q++) {
        int idx = lane * 4 + q;
        s = fmaf(bq[idx], sT2[idx], s);
      }
#pragma unroll
      for (int m = 1; m <= 32; m <<= 1) s += __shfl_xor(s, m);
      if (lane == 0) ws[WS_C1] = s;
    }
  }
}

// =====================================================================
// K_qkg: init only (slots = mu + sigma*noise; qkg/qb for iter 0)
// =====================================================================
__global__ __launch_bounds__(256) void k_qkg(
    const float* __restrict__ noise, const float* __restrict__ mu,
    const float* __restrict__ sigma, const float* __restrict__ g_s,
    const float* __restrict__ be_s, float* __restrict__ ws, int init)
{
  __shared__ __align__(16) float sS[16 * 260];
  __shared__ __align__(16) float sAux[512];
  __shared__ __align__(16) float sStat[32];
  int bid = blockIdx.x, t = threadIdx.x;
  for (int n = 0; n < 16; n++) {
    float v;
    if (init) v = fmaf(sigma[t], noise[n * 256 + t], mu[t]);
    else      v = ws[WS_SLOTS + n * 256 + t];
    sS[n * 260 + t] = v;
    if (init && bid == 0) ws[WS_SLOTS + n * 256 + t] = v;
  }
  __syncthreads();
  { int n = t >> 4, c = t & 15;
    float s1 = 0.f, s2 = 0.f;
    for (int k = 0; k < 16; k++) {
      float x = sS[n * 260 + c * 16 + k];
      s1 += x; s2 = fmaf(x, x, s2);
    }
    sAux[n * 16 + c] = s1; sAux[256 + n * 16 + c] = s2; }
  __syncthreads();
  if (t < 16) {
    float s1 = 0.f, s2 = 0.f;
    for (int c = 0; c < 16; c++) { s1 += sAux[t * 16 + c]; s2 += sAux[256 + t * 16 + c]; }
    float m = s1 * (1.f / 256.f);
    float v = fmaxf(fmaf(-m, m, s2 * (1.f / 256.f)), 0.f);
    sStat[t] = m; sStat[16 + t] = rsqrtf(v + LN_EPS);
  }
  __syncthreads();
  { float gs = g_s[t], bs = be_s[t];
    for (int n = 0; n < 16; n++) {
      float m = sStat[n], rs = sStat[16 + n];
      sS[n * 260 + t] = fmaf((sS[n * 260 + t] - m) * rs, gs, bs);
    } }
  __syncthreads();
  if (bid < 64) {
    int cr = t >> 6, n = (t >> 2) & 15, ks = t & 3;
    int c = bid * 4 + cr;
    const float* wrow = ws + WS_WQKG + c * 256 + ks * 64;
    const float* srow = &sS[n * 260 + ks * 64];
    float acc = 0.f;
#pragma unroll
    for (int i = 0; i < 16; i++) {
      float4 w = *(const float4*)(wrow + i * 4);
      float4 s4 = *(const float4*)(srow + i * 4);
      acc = fmaf(w.x, s4.x, fmaf(w.y, s4.y, fmaf(w.z, s4.z, fmaf(w.w, s4.w, acc))));
    }
    sAux[t] = acc;
    __syncthreads();
    if (t < 64) {
      int cr2 = t >> 4, n2 = t & 15;
      int c2 = bid * 4 + cr2;
      int b = cr2 * 64 + n2 * 4;
      float s = sAux[b] + sAux[b + 1] + sAux[b + 2] + sAux[b + 3];
      ws[WS_QKG + n2 * 256 + c2] = s + ws[WS_U2G + c2];
    }
  } else {
    int n = t >> 4, ks = t & 15;
    float acc = 0.f;
    for (int k = 0; k < 16; k++)
      acc = fmaf(sS[n * 260 + ks * 16 + k], ws[WS_U1 + ks * 16 + k], acc);
    sAux[t] = acc;
    __syncthreads();
    if (t < 16) {
      float s = 0.f;
      for (int k = 0; k < 16; k++) s += sAux[t * 16 + k];
      ws[WS_QB + t] = SCALE * (s + ws[WS_C1]);
    }
  }
}

// =====================================================================
// K_big: R11 form unchanged (105.5us, VALUBusy 48%, VGPR 108).
// pair-ILP + distance-1 prefetch + merged 12-var butterfly;
// epilogue atomicAdds into 8 slices (slice = bid & 7).
// =====================================================================
__global__ __launch_bounds__(512, 2) void k_big(
    const float* __restrict__ X, float* __restrict__ ws)
{
  __shared__ __align__(16) float red[4 * 4096];   // 64 KB
  __shared__ __align__(16) float redS[128];       // 8 waves x 16
  int t = threadIdx.x;
  int wave = t >> 6, lane = t & 63;
  int p = lane >> 4, g = lane & 15;

  const float* qkg = ws + WS_QKG;
  float qw[4][16];
  float qs[4];
#pragma unroll
  for (int i = 0; i < 4; i++) {
    const float* rp = qkg + (4 * p + i) * 256 + g * 16;
#pragma unroll
    for (int jq = 0; jq < 4; jq++) {
      float4 v4 = *(const float4*)(rp + 4 * jq);
      qw[i][4 * jq + 0] = v4.x; qw[i][4 * jq + 1] = v4.y;
      qw[i][4 * jq + 2] = v4.z; qw[i][4 * jq + 3] = v4.w;
    }
    float s = 0.f;
#pragma unroll
    for (int j = 0; j < 16; j++) s += qw[i][j];
    qs[i] = s;
  }
#pragma unroll
  for (int m = 1; m <= 8; m <<= 1) {
#pragma unroll
    for (int i = 0; i < 4; i++) qs[i] += __shfl_xor(qs[i], m);
  }
  float qb0[4];
  {
    float4 q4 = *(const float4*)(ws + WS_QB + 4 * p);
    qb0[0] = q4.x; qb0[1] = q4.y; qb0[2] = q4.z; qb0[3] = q4.w;
  }

  float P[4][16];
#pragma unroll
  for (int i = 0; i < 4; i++)
#pragma unroll
    for (int j = 0; j < 16; j++) P[i][j] = 0.f;
  float Q[4] = {0.f, 0.f, 0.f, 0.f};
  float Sa[4] = {0.f, 0.f, 0.f, 0.f};

  size_t rowbase = (size_t)blockIdx.x * ROWS_PER_BLOCK + (size_t)wave * ROWS_PER_WAVE;
  const float* base = X + rowbase * 256 + g * 16;

  float4 cA0 = *(const float4*)(base + 0);
  float4 cB0 = *(const float4*)(base + 4);
  float4 cC0 = *(const float4*)(base + 8);
  float4 cD0 = *(const float4*)(base + 12);
  float4 cA1 = *(const float4*)(base + 256);
  float4 cB1 = *(const float4*)(base + 260);
  float4 cC1 = *(const float4*)(base + 264);
  float4 cD1 = *(const float4*)(base + 268);

#pragma unroll 1
  for (int r = 0; r < ROWS_PER_WAVE; r += 2) {
    const float* nx = base + (size_t)((r + 2 < ROWS_PER_WAVE) ? (r + 2) : 0) * 256;
    float4 pA0 = *(const float4*)(nx + 0);
    float4 pB0 = *(const float4*)(nx + 4);
    float4 pC0 = *(const float4*)(nx + 8);
    float4 pD0 = *(const float4*)(nx + 12);
    float4 pA1 = *(const float4*)(nx + 256);
    float4 pB1 = *(const float4*)(nx + 260);
    float4 pC1 = *(const float4*)(nx + 264);
    float4 pD1 = *(const float4*)(nx + 268);

    float x0[16], x1[16];
    x0[0] = cA0.x; x0[1] = cA0.y; x0[2] = cA0.z; x0[3] = cA0.w;
    x0[4] = cB0.x; x0[5] = cB0.y; x0[6] = cB0.z; x0[7] = cB0.w;
    x0[8] = cC0.x; x0[9] = cC0.y; x0[10] = cC0.z; x0[11] = cC0.w;
    x0[12] = cD0.x; x0[13] = cD0.y; x0[14] = cD0.z; x0[15] = cD0.w;
    x1[0] = cA1.x; x1[1] = cA1.y; x1[2] = cA1.z; x1[3] = cA1.w;
    x1[4] = cB1.x; x1[5] = cB1.y; x1[6] = cB1.z; x1[7] = cB1.w;
    x1[8] = cC1.x; x1[9] = cC1.y; x1[10] = cC1.z; x1[11] = cC1.w;
    x1[12] = cD1.x; x1[13] = cD1.y; x1[14] = cD1.z; x1[15] = cD1.w;

    // ---- partial sums: stats AND dots together (12 parallel chains) ----
    float s10 = 0.f, s20 = 0.f, s11 = 0.f, s21 = 0.f;
    float d0[4] = {0.f, 0.f, 0.f, 0.f};
    float d1[4] = {0.f, 0.f, 0.f, 0.f};
#pragma unroll
    for (int j = 0; j < 16; j++) {
      s10 += x0[j]; s20 = fmaf(x0[j], x0[j], s20);
      s11 += x1[j]; s21 = fmaf(x1[j], x1[j], s21);
#pragma unroll
      for (int i = 0; i < 4; i++) {
        d0[i] = fmaf(qw[i][j], x0[j], d0[i]);
        d1[i] = fmaf(qw[i][j], x1[j], d1[i]);
      }
    }
    // ---- ONE merged 12-var butterfly (4 levels over 16 lanes) ----
#pragma unroll
    for (int m = 1; m <= 8; m <<= 1) {
      s10 += __shfl_xor(s10, m); s11 += __shfl_xor(s11, m);
      s20 += __shfl_xor(s20, m); s21 += __shfl_xor(s21, m);
#pragma unroll
      for (int i = 0; i < 4; i++) {
        d0[i] += __shfl_xor(d0[i], m);
        d1[i] += __shfl_xor(d1[i], m);
      }
    }
    float mean0 = s10 * (1.f / 256.f), mean1 = s11 * (1.f / 256.f);
    float var0 = fmaxf(fmaf(-mean0, mean0, s20 * (1.f / 256.f)), 0.f);
    float var1 = fmaxf(fmaf(-mean1, mean1, s21 * (1.f / 256.f)), 0.f);
    float rs0 = rsqrtf(var0 + LN_EPS), rs1 = rsqrtf(var1 + LN_EPS);
    float mrs0 = mean0 * rs0, mrs1 = mean1 * rs1;

    float dsc0[4], dsc1[4];
#pragma unroll
    for (int i = 0; i < 4; i++) {
      dsc0[i] = fmaf(rs0, d0[i], fmaf(-mrs0, qs[i], qb0[i]));
      dsc1[i] = fmaf(rs1, d1[i], fmaf(-mrs1, qs[i], qb0[i]));
    }

    // ---- softmax, both rows interleaved ----
    float mx0 = fmaxf(fmaxf(dsc0[0], dsc0[1]), fmaxf(dsc0[2], dsc0[3]));
    float mx1 = fmaxf(fmaxf(dsc1[0], dsc1[1]), fmaxf(dsc1[2], dsc1[3]));
    mx0 = fmaxf(mx0, __shfl_xor(mx0, 16)); mx1 = fmaxf(mx1, __shfl_xor(mx1, 16));
    mx0 = fmaxf(mx0, __shfl_xor(mx0, 32)); mx1 = fmaxf(mx1, __shfl_xor(mx1, 32));
    float e0[4], e1[4];
#pragma unroll
    for (int i = 0; i < 4; i++) {
      e0[i] = __expf(dsc0[i] - mx0);
      e1[i] = __expf(dsc1[i] - mx1);
    }
    float se0 = e0[0] + e0[1] + e0[2] + e0[3];
    float se1 = e1[0] + e1[1] + e1[2] + e1[3];
    se0 += __shfl_xor(se0, 16); se1 += __shfl_xor(se1, 16);
    se0 += __shfl_xor(se0, 32); se1 += __shfl_xor(se1, 32);
    float inv0 = 1.0f / se0, inv1 = 1.0f / se1;
    float a0v[4], ar0[4], a1v[4], ar1[4];
#pragma unroll
    for (int i = 0; i < 4; i++) {
      a0v[i] = fmaf(e0[i], inv0, ATTN_EPS); ar0[i] = a0v[i] * rs0;
      a1v[i] = fmaf(e1[i], inv1, ATTN_EPS); ar1[i] = a1v[i] * rs1;
    }

    // ---- P accumulation (shared accumulators, row r then r+1) ----
#pragma unroll
    for (int j = 0; j < 16; j++) {
#pragma unroll
      for (int i = 0; i < 4; i++) {
        P[i][j] = fmaf(ar0[i], x0[j], P[i][j]);
        P[i][j] = fmaf(ar1[i], x1[j], P[i][j]);
      }
    }
#pragma unroll
    for (int i = 0; i < 4; i++) {
      Q[i] = fmaf(a0v[i], mrs0, Q[i]);
      Q[i] = fmaf(a1v[i], mrs1, Q[i]);
      Sa[i] += a0v[i];
      Sa[i] += a1v[i];
    }

    cA0 = pA0; cB0 = pB0; cC0 = pC0; cD0 = pD0;
    cA1 = pA1; cB1 = pB1; cC1 = pC1; cD1 = pD1;
  }

  // Two-stage cross-wave reduce in 64KB LDS (Uy = P - Q per slot/elem).
  int slot = wave & 3;
  if (wave < 4) {
#pragma unroll
    for (int i = 0; i < 4; i++) {
#pragma unroll
      for (int jq = 0; jq < 4; jq++) {
        float4 v4;
        v4.x = P[i][4 * jq + 0] - Q[i]; v4.y = P[i][4 * jq + 1] - Q[i];
        v4.z = P[i][4 * jq + 2] - Q[i]; v4.w = P[i][4 * jq + 3] - Q[i];
        *(float4*)&red[slot * 4096 + (4 * p + i) * 256 + g * 16 + jq * 4] = v4;
      }
    }
  }
  if (g == 0) {
#pragma unroll
    for (int i = 0; i < 4; i++) redS[wave * 16 + 4 * p + i] = Sa[i];
  }
  __syncthreads();
  if (wave >= 4) {
#pragma unroll
    for (int i = 0; i < 4; i++) {
#pragma unroll
      for (int jq = 0; jq < 4; jq++) {
        float4* dst = (float4*)&red[slot * 4096 + (4 * p + i) * 256 + g * 16 + jq * 4];
        float4 c = *dst;
        c.x += P[i][4 * jq + 0] - Q[i]; c.y += P[i][4 * jq + 1] - Q[i];
        c.z += P[i][4 * jq + 2] - Q[i]; c.w += P[i][4 * jq + 3] - Q[i];
        *dst = c;
      }
    }
  }
  __syncthreads();
  int slice = blockIdx.x & 7;
#pragma unroll
  for (int k = 0; k < 8; k++) {
    int idx = k * 512 + t;
    float v = red[idx] + red[4096 + idx] + red[8192 + idx] + red[12288 + idx];
    atomicAdd(&ws[WS_PARTU + (size_t)slice * 4096 + idx], v);
  }
  if (t < 16) {
    float sv = 0.f;
#pragma unroll
    for (int w = 0; w < 8; w++) sv += redS[w * 16 + t];
    atomicAdd(&ws[WS_PARTS + slice * 16 + t], sv);
  }
}

// =====================================================================
// K_gxgh: unchanged from R11 — gx blocks inline-reduce 8 slices.
// bid<64:  gx[n][j] = W_ihv[j]·(g_in*(U[n]/S[n]) + be_in) + bgx[j]
// bid>=64: gh[n][j] = W_hh[j]·slots_prev[n] + b_hh[j]
// =====================================================================
__global__ __launch_bounds__(256) void k_gxgh(
    const float* __restrict__ W_hh, const float* __restrict__ b_hh,
    const float* __restrict__ g_in, const float* __restrict__ be_in,
    float* __restrict__ ws)
{
  __shared__ __align__(16) float sU[16 * 260];
  __shared__ __align__(16) float sInv[16];
  int bid = blockIdx.x, t = threadIdx.x;
  bool isgx = bid < 64;
  if (isgx && t < 16) {
    float s = 0.f;
#pragma unroll
    for (int sl = 0; sl < NSLICE; sl++) s += ws[WS_PARTS + sl * 16 + t];
    sInv[t] = 1.0f / s;
  }
  __syncthreads();
  if (isgx) {
    float gi = g_in[t], bi = be_in[t];
    for (int n = 0; n < 16; n++) {
      float acc = 0.f;
#pragma unroll
      for (int sl = 0; sl < NSLICE; sl++)
        acc += ws[WS_PARTU + (size_t)sl * 4096 + n * 256 + t];
      sU[n * 260 + t] = fmaf(gi * acc, sInv[n], bi);
    }
  } else {
    for (int n = 0; n < 16; n++)
      sU[n * 260 + t] = ws[WS_SLOTS + n * 256 + t];
  }
  __syncthreads();
  int jr = t >> 4, n = t & 15;
  if (jr < 12) {
    int j = (isgx ? bid : bid - 64) * 12 + jr;
    const float* srow = &sU[n * 260];
    const float* wrow = isgx ? (ws + WS_WIHV + j * 256) : (W_hh + j * 256);
    float acc = isgx ? ws[WS_BGX + j] : b_hh[j];
#pragma unroll 8
    for (int k = 0; k < 64; k++) {
      float4 w = *(const float4*)(wrow + k * 4);
      float4 s4 = *(const float4*)(srow + k * 4);
      acc = fmaf(w.x, s4.x, fmaf(w.y, s4.y, fmaf(w.z, s4.z, fmaf(w.w, s4.w, acc))));
    }
    if (isgx) ws[WS_GX + n * 768 + j] = acc;
    else      ws[WS_GH + n * 768 + j] = acc;
  }
}

// =====================================================================
// K_tail: fused midh1+ffnew+qkg, one block per slot (16 x 512).
// Per-slot independent — __syncthreads only, no grid barrier.
// Weight reads per block: W1+W2+WQKG = 768KB (vs R6's fatal 2.3MB;
// the weight-heavy gx/gh stays in k_gxgh). Also re-zeros the 8
// PARTU/PARTS slices for the next iteration's k_big.
// Phases: Z zero; A GRU->mid; B LN(g_f)->lnf; C h1=relu(W1·lnf+b1);
// D new=mid+W2·h1+b2 ->SLOTS,out; E (if !last) LN(g_s)->s, qkg, qb.
// =====================================================================
__global__ __launch_bounds__(512) void k_tail(
    const float* __restrict__ W1, const float* __restrict__ b1,
    const float* __restrict__ g_f, const float* __restrict__ be_f,
    const float* __restrict__ W2, const float* __restrict__ b2v,
    const float* __restrict__ g_s, const float* __restrict__ be_s,
    float* __restrict__ out, float* __restrict__ ws, int last)
{
  __shared__ __align__(16) float sMid[256];
  __shared__ __align__(16) float sVec[256];
  __shared__ __align__(16) float sH1[256];
  __shared__ __align__(16) float sNew[256];
  __shared__ __align__(16) float sR[32];
  int n = blockIdx.x, t = threadIdx.x;
  int wv = t >> 6, lane = t & 63;
  int j16 = t >> 4, kt = t & 15;     // 32 row-groups x 16 k-lanes

  // ---- phase Z: zero the 8 atomic slices for next k_big ----
  {
    int gid = n * 512 + t;           // 0..8191
    float4 z4 = {0.f, 0.f, 0.f, 0.f};
    *(float4*)&ws[WS_PARTU + gid * 4] = z4;   // 8192*4 = 32768 = 8*4096
    if (n == 0 && t < 128) ws[WS_PARTS + t] = 0.f;
  }

  // ---- phase A: GRU -> mid ----
  float mid = 0.f;
  if (t < 256) {
    float xr = ws[WS_GX + n * 768 + t],       hr = ws[WS_GH + n * 768 + t];
    float xz = ws[WS_GX + n * 768 + 256 + t], hz = ws[WS_GH + n * 768 + 256 + t];
    float xn = ws[WS_GX + n * 768 + 512 + t], hn = ws[WS_GH + n * 768 + 512 + t];
    float sp = ws[WS_SLOTS + n * 256 + t];
    float r = 1.f / (1.f + __expf(-(xr + hr)));
    float z = 1.f / (1.f + __expf(-(xz + hz)));
    float nn = tanhf(fmaf(r, hn, xn));
    mid = fmaf(z, sp - nn, nn);
    sMid[t] = mid;
  }

  // ---- phase B: LN(g_f, be_f) -> sVec ----
  {
    float s1 = mid, s2 = mid * mid;   // zero for t>=256
#pragma unroll
    for (int m = 1; m <= 32; m <<= 1) {
      s1 += __shfl_xor(s1, m); s2 += __shfl_xor(s2, m);
    }
    if (lane == 0) { sR[wv] = s1; sR[8 + wv] = s2; }
  }
  __syncthreads();
  {
    float s1 = sR[0] + sR[1] + sR[2] + sR[3] + sR[4] + sR[5] + sR[6] + sR[7];
    float s2 = sR[8] + sR[9] + sR[10] + sR[11] + sR[12] + sR[13] + sR[14] + sR[15];
    float mean = s1 * (1.f / 256.f);
    float var = fmaxf(fmaf(-mean, mean, s2 * (1.f / 256.f)), 0.f);
    float rs = rsqrtf(var + LN_EPS);
    if (t < 256)
      sVec[t] = fmaf((sMid[t] - mean) * rs, g_f[t], be_f[t]);
  }
  __syncthreads();

  // ---- phase C: h1 = relu(W1·lnf + b1) (8 passes x 32 rows) ----
#pragma unroll 2
  for (int pass = 0; pass < 8; pass++) {
    int j = pass * 32 + j16;
    float a = dot16(W1 + (size_t)j * 256 + kt * 16, sVec + kt * 16);
    a += __shfl_xor(a, 1); a += __shfl_xor(a, 2);
    a += __shfl_xor(a, 4); a += __shfl_xor(a, 8);
    if (kt == 0) sH1[j] = fmaxf(a + b1[j], 0.f);
  }
  __syncthreads();

  // ---- phase D: new = mid + W2·h1 + b2 -> SLOTS, out ----
#pragma unroll 2
  for (int pass = 0; pass < 8; pass++) {
    int d = pass * 32 + j16;
    float a = dot16(W2 + (size_t)d * 256 + kt * 16, sH1 + kt * 16);
    a += __shfl_xor(a, 1); a += __shfl_xor(a, 2);
    a += __shfl_xor(a, 4); a += __shfl_xor(a, 8);
    if (kt == 0) sNew[d] = a + b2v[d] + sMid[d];
  }
  __syncthreads();
  if (t < 256) {
    float v = sNew[t];
    ws[WS_SLOTS + n * 256 + t] = v;
    out[n * 256 + t] = v;
  }
  if (last) return;

  // ---- phase E: LN(g_s) -> s; qkg row; qb ----
  {
    float v = (t < 256) ? sNew[t] : 0.f;
    float s1 = v, s2 = v * v;
#pragma unroll
    for (int m = 1; m <= 32; m <<= 1) {
      s1 += __shfl_xor(s1, m); s2 += __shfl_xor(s2, m);
    }
    if (lane == 0) { sR[wv] = s1; sR[8 + wv] = s2; }
  }
  __syncthreads();
  {
    float s1 = sR[0] + sR[1] + sR[2] + sR[3] + sR[4] + sR[5] + sR[6] + sR[7];
    float s2 = sR[8] + sR[9] + sR[10] + sR[11] + sR[12] + sR[13] + sR[14] + sR[15];
    float mean = s1 * (1.f / 256.f);
    float var = fmaxf(fmaf(-mean, mean, s2 * (1.f / 256.f)), 0.f);
    float rs = rsqrtf(var + LN_EPS);
    if (t < 256)
      sVec[t] = fmaf((sNew[t] - mean) * rs, g_s[t], be_s[t]);
  }
  __syncthreads();
#pragma unroll 2
  for (int pass = 0; pass < 8; pass++) {
    int c = pass * 32 + j16;
    float a = dot16(ws + WS_WQKG + (size_t)c * 256 + kt * 16, sVec + kt * 16);
    a += __shfl_xor(a, 1); a += __shfl_xor(a, 2);
    a += __shfl_xor(a, 4); a += __shfl_xor(a, 8);
    if (kt == 0) ws[WS_QKG + n * 256 + c] = a + ws[WS_U2G + c];
  }
  {
    float pq = (t < 256) ? sVec[t] * ws[WS_U1 + t] : 0.f;
#pragma unroll
    for (int m = 1; m <= 32; m <<= 1) pq += __shfl_xor(pq, m);
    if (lane == 0) sR[wv] = pq;
  }
  __syncthreads();
  if (t == 0) {
    float s = sR[0] + sR[1] + sR[2] + sR[3] + sR[4] + sR[5] + sR[6] + sR[7];
    ws[WS_QB + n] = SCALE * (s + ws[WS_C1]);
  }
}

// =====================================================================
extern "C" void kernel_launch(void* const* d_in, const int* in_sizes, int n_in,
                              void* d_out, int out_size, void* d_ws, size_t ws_size,
                              hipStream_t stream)
{
  (void)in_sizes; (void)n_in; (void)out_size; (void)ws_size;
  const float* inputs = (const float*)d_in[0];
  const float* noise  = (const float*)d_in[1];
  const float* mu     = (const float*)d_in[2];
  const float* sigma  = (const float*)d_in[3];
  const float* Wq     = (const float*)d_in[4];
  const float* bq     = (const float*)d_in[5];
  const float* Wk     = (const float*)d_in[6];
  const float* bk     = (const float*)d_in[7];
  const float* Wv     = (const float*)d_in[8];
  const float* bv     = (const float*)d_in[9];
  const float* W_ih   = (const float*)d_in[10];
  const float* W_hh   = (const float*)d_in[11];
  const float* b_ih   = (const float*)d_in[12];
  const float* b_hh   = (const float*)d_in[13];
  const float* W1     = (const float*)d_in[14];
  const float* b1     = (const float*)d_in[15];
  const float* W2     = (const float*)d_in[16];
  const float* b2     = (const float*)d_in[17];
  const float* g_in   = (const float*)d_in[18];
  const float* be_in  = (const float*)d_in[19];
  const float* g_s    = (const float*)d_in[20];
  const float* be_s   = (const float*)d_in[21];
  const float* g_f    = (const float*)d_in[22];
  const float* be_f   = (const float*)d_in[23];
  float* ws = (float*)d_ws;
  float* out = (float*)d_out;

  hipLaunchKernelGGL(k_pre1, dim3(257), dim3(256), 0, stream,
                     Wq, bq, Wk, bk, Wv, bv, W_ih, b_ih, g_in, be_in, ws);
  hipLaunchKernelGGL(k_qkg, dim3(65), dim3(256), 0, stream,
                     noise, mu, sigma, g_s, be_s, ws, 1);
  for (int it = 0; it < 3; it++) {
    hipLaunchKernelGGL(k_big, dim3(BIG_BLOCKS), dim3(BIG_THREADS), 0, stream,
                       inputs, ws);
    hipLaunchKernelGGL(k_gxgh, dim3(128), dim3(256), 0, stream,
                       W_hh, b_hh, g_in, be_in, ws);
    hipLaunchKernelGGL(k_tail, dim3(16), dim3(512), 0, stream,
                       W1, b1, g_f, be_f, W2, b2, g_s, be_s,
                       out, ws, (it == 2) ? 1 : 0);
  }
}